// Round 3
// 10105.628 us; speedup vs baseline: 1.4344x; 1.4344x over previous
//
#include <hip/hip_runtime.h>

typedef unsigned short u16;
typedef unsigned int u32;

// ---------- bf16 <-> fp32 helpers (LDS staging only; global I/O is fp32) ----------
__device__ __forceinline__ float b2f(u16 v) { return __uint_as_float(((u32)v) << 16); }
__device__ __forceinline__ u16 f2b(float f) {
  u32 u = __float_as_uint(f);
  u32 r = (u + 0x7fffu + ((u >> 16) & 1u)) >> 16;  // RNE
  return (u16)r;
}
__device__ __forceinline__ void unpack8(uint4 u, float* f) {
  f[0] = __uint_as_float(u.x << 16);
  f[1] = __uint_as_float(u.x & 0xffff0000u);
  f[2] = __uint_as_float(u.y << 16);
  f[3] = __uint_as_float(u.y & 0xffff0000u);
  f[4] = __uint_as_float(u.z << 16);
  f[5] = __uint_as_float(u.z & 0xffff0000u);
  f[6] = __uint_as_float(u.w << 16);
  f[7] = __uint_as_float(u.w & 0xffff0000u);
}
__device__ __forceinline__ uint4 pack8(const u16* o) {
  return make_uint4((u32)o[0] | ((u32)o[1] << 16), (u32)o[2] | ((u32)o[3] << 16),
                    (u32)o[4] | ((u32)o[5] << 16), (u32)o[6] | ((u32)o[7] << 16));
}
__device__ __forceinline__ void load8f(const float* p, float* f) {
  *(float4*)(f) = *(const float4*)(p);
  *(float4*)(f + 4) = *(const float4*)(p + 4);
}

// ---------- fused [dw3x3+BN+res] -> [1x1 BN relu] -> [1x1 BN + res] ----------
// Y = X1 + FFN(X1), X1 = X + bn(dw3x3(X)), for a 32-pixel chunk of one batch.
// Src and Dst MUST differ (halo reads cross block boundaries).
// LDS: Xs 16 KiB (bf16) + Hs 32 KiB (bf16) = 48 KiB -> 3 blocks/CU.
__global__ __launch_bounds__(256) void dwffn(const float* __restrict__ X, float* __restrict__ Y,
                                             const float* __restrict__ DwW, const float* __restrict__ DwS,
                                             const float* __restrict__ DwB, const float* __restrict__ W1,
                                             const float* __restrict__ S1, const float* __restrict__ B1,
                                             const float* __restrict__ W2, const float* __restrict__ S2,
                                             const float* __restrict__ B2) {
  __shared__ __align__(16) u16 Xs[256][32];  // X1 tile  [c][p], bf16
  __shared__ __align__(16) u16 Hs[512][32];  // hidden   [hm][p], bf16
  const int tid = threadIdx.x;
  const int pix0 = blockIdx.x << 5;                // pixel chunk start in the 4096-pixel plane
  const long zbase = (long)blockIdx.y * 1048576L;  // batch offset (256*4096 elements)
  const int h0 = pix0 >> 6, w0 = pix0 & 63;        // chunk = half of one image row

  // phase A: X1 = x + s*dw3x3(x) + b   (zero-padded SAME conv)
  for (int i = tid; i < 256 * 32; i += 256) {
    int c = i >> 5, p = i & 31;
    int w = w0 + p;
    const float* xp = X + zbase + (long)c * 4096;
    float acc = 0.f;
#pragma unroll
    for (int u = 0; u < 3; u++) {
      int hh = h0 + u - 1;
      if (hh < 0 || hh > 63) continue;
#pragma unroll
      for (int v = 0; v < 3; v++) {
        int wv = w + v - 1;
        if (wv < 0 || wv > 63) continue;
        acc = fmaf(DwW[c * 9 + u * 3 + v], xp[hh * 64 + wv], acc);
      }
    }
    float x1 = xp[h0 * 64 + w] + fmaf(DwS[c], acc, DwB[c]);
    Xs[c][p] = f2b(x1);
  }
  __syncthreads();

  // phase B: hidden[hm][p] = relu(s1*Σ_c w1[hm][c]*X1[c][p] + b1); rows hm and hm+256 per thread
  {
    const int hm = tid, hm2 = tid + 256;
    float acc0[32], acc1[32];
#pragma unroll
    for (int p = 0; p < 32; p++) { acc0[p] = 0.f; acc1[p] = 0.f; }
    const float* wr0 = W1 + hm * 256;
    const float* wr1 = W1 + hm2 * 256;
    for (int c0 = 0; c0 < 256; c0 += 8) {
      float wf0[8], wf1[8];
      load8f(wr0 + c0, wf0);
      load8f(wr1 + c0, wf1);
#pragma unroll
      for (int e = 0; e < 8; e++) {
        const u16* xr = &Xs[c0 + e][0];
#pragma unroll
        for (int pc = 0; pc < 4; pc++) {
          float xf[8];
          unpack8(*(const uint4*)(xr + (pc << 3)), xf);
#pragma unroll
          for (int j = 0; j < 8; j++) {
            acc0[(pc << 3) + j] = fmaf(wf0[e], xf[j], acc0[(pc << 3) + j]);
            acc1[(pc << 3) + j] = fmaf(wf1[e], xf[j], acc1[(pc << 3) + j]);
          }
        }
      }
    }
    float s0 = S1[hm], b0 = B1[hm], s1v = S1[hm2], b1v = B1[hm2];
#pragma unroll
    for (int pc = 0; pc < 4; pc++) {
      u16 o0[8], o1[8];
#pragma unroll
      for (int j = 0; j < 8; j++) {
        o0[j] = f2b(fmaxf(fmaf(s0, acc0[(pc << 3) + j], b0), 0.f));
        o1[j] = f2b(fmaxf(fmaf(s1v, acc1[(pc << 3) + j], b1v), 0.f));
      }
      *(uint4*)&Hs[hm][pc << 3] = pack8(o0);
      *(uint4*)&Hs[hm2][pc << 3] = pack8(o1);
    }
  }
  __syncthreads();

  // phase C: out[co][p] = s2*Σ_h w2[co][h]*H[h][p] + b2 + X1[co][p]
  {
    const int co = tid;
    float acc[32];
#pragma unroll
    for (int p = 0; p < 32; p++) acc[p] = 0.f;
    const float* wr = W2 + co * 512;
    for (int h8 = 0; h8 < 512; h8 += 8) {
      float wf[8];
      load8f(wr + h8, wf);
#pragma unroll
      for (int e = 0; e < 8; e++) {
        const u16* hr = &Hs[h8 + e][0];
#pragma unroll
        for (int pc = 0; pc < 4; pc++) {
          float xf[8];
          unpack8(*(const uint4*)(hr + (pc << 3)), xf);
#pragma unroll
          for (int j = 0; j < 8; j++) acc[(pc << 3) + j] = fmaf(wf[e], xf[j], acc[(pc << 3) + j]);
        }
      }
    }
    float s = S2[co], b = B2[co];
    long obase = zbase + (long)co * 4096 + pix0;
#pragma unroll
    for (int pc = 0; pc < 4; pc++) {
      float rf[8];
      unpack8(*(const uint4*)&Xs[co][pc << 3], rf);
      float o[8];
#pragma unroll
      for (int j = 0; j < 8; j++) o[j] = fmaf(s, acc[(pc << 3) + j], b) + rf[j];
      *(float4*)(Y + obase + (pc << 3)) = *(float4*)(o);
      *(float4*)(Y + obase + (pc << 3) + 4) = *(float4*)(o + 4);
    }
  }
}

// ---------- fused windowed focused-linear attention (src != dst) ----------
// one block (512 threads) per window (3200 windows of 49 tokens x 256 ch).
// LDS map (158,064 B total, 1 block/CU, 8 waves/CU):
//   SQ  fp32 49xKS   [0, 51744)
//   SK  bf16 49xKS   [51744, 77616)
//   SV  bf16 49xKS   [77616, 103488)
//   SXW fp32 49xKS   [103488, 155232)  -- dead after projections; then:
//     SQK fp32 49x50   [103488, 113288)  (alias)
//     SDW fp32 1664    [113288, 119944)  (dwc 5x5 weights + bias, alias)
//   SSC fp32 256, SKS fp32 256, SZ fp32 196
#define NTOK 49
#define KS 264  // LDS token stride (elements); 16B-aligned rows
#define OFF_SK (NTOK * KS * 4)              // SQ: fp32 49xKS
#define OFF_SV (OFF_SK + NTOK * KS * 2)     // SK: bf16
#define OFF_SXW (OFF_SV + NTOK * KS * 2)    // SV: bf16
#define OFF_SQK (OFF_SXW)                   // alias: SQK over dead SXW
#define OFF_SDW (OFF_SXW + NTOK * 50 * 4 + 88)  // 113288: dwc weights, 16B aligned
#define OFF_SSC (OFF_SXW + NTOK * KS * 4)   // 155232
#define OFF_SKS (OFF_SSC + 256 * 4)
#define OFF_SZ (OFF_SKS + 256 * 4)
#define SMEM_BYTES (OFF_SZ + 4 * NTOK * 4)  // 158,064 B (< 160 KiB)

__global__ __launch_bounds__(512) void attn_kernel(const float* __restrict__ X, const float* __restrict__ Wq,
                                                   const float* __restrict__ Wkv, const float* __restrict__ Pos,
                                                   const float* __restrict__ ScaleP, const float* __restrict__ DwcW,
                                                   const float* __restrict__ DwcB, const float* __restrict__ PrW,
                                                   const float* __restrict__ PrB, float* __restrict__ Y) {
  extern __shared__ char smem[];
  float* SQ = (float*)(smem);
  u16* SK = (u16*)(smem + OFF_SK);
  u16* SV = (u16*)(smem + OFF_SV);
  float* SXW = (float*)(smem + OFF_SXW);
  float* SQK = (float*)(smem + OFF_SQK);
  float* SDW = (float*)(smem + OFF_SDW);
  float* SSC = (float*)(smem + OFF_SSC);
  float* SKS = (float*)(smem + OFF_SKS);
  float* SZ = (float*)(smem + OFF_SZ);

  const int tid = threadIdx.x;
  const int wi = blockIdx.x;
  const int b = wi / 100;
  const int rem = wi - b * 100;
  const int wh = rem / 10, ww = rem - (rem / 10) * 10;
  const long bbase = (long)b * (256L * 4096L);

  // softplus(scale_p) per channel
  if (tid < 256) SSC[tid] = log1pf(expf(ScaleP[tid]));

  // gather window (zero-padded) into LDS, token-major, fp32
  for (int i = tid; i < NTOK * 256; i += 512) {
    int c = i / NTOK, t = i - c * NTOK;
    int r = t / 7, cc = t - r * 7;
    int gh = wh * 7 + r, gw = ww * 7 + cc;
    float v = 0.f;
    if (gh < 64 && gw < 64) v = X[bbase + (long)c * 4096 + gh * 64 + gw];
    SXW[t * KS + c] = v;
  }
  __syncthreads();

  // q / kv projections (fp32 LDS reads, no unpack in the inner loop)
  for (int w = tid; w < 768 * 7; w += 512) {
    int j = w / 7, tg = w - j * 7;
    const float* wrow = (j < 256) ? (Wq + j * 256) : (Wkv + (j - 256) * 256);
    float acc[7] = {0.f, 0.f, 0.f, 0.f, 0.f, 0.f, 0.f};
    for (int c = 0; c < 256; c += 8) {
      float wf[8];
      load8f(wrow + c, wf);
#pragma unroll
      for (int s = 0; s < 7; s++) {
        float xf[8];
        load8f(SXW + (tg * 7 + s) * KS + c, xf);
        float a = acc[s];
#pragma unroll
        for (int e = 0; e < 8; e++) a = fmaf(wf[e], xf[e], a);
        acc[s] = a;
      }
    }
    if (j < 256) {
      float sc = SSC[j];
#pragma unroll
      for (int s = 0; s < 7; s++) {
        int t = tg * 7 + s;
        SQ[t * KS + j] = (fmaxf(acc[s], 0.f) + 1e-6f) / sc;
      }
    } else if (j < 512) {
      int kc = j - 256;
      float sc = SSC[kc];
#pragma unroll
      for (int s = 0; s < 7; s++) {
        int t = tg * 7 + s;
        float v = acc[s] + Pos[t * 256 + kc];
        SK[t * KS + kc] = f2b((fmaxf(v, 0.f) + 1e-6f) / sc);
      }
    } else {
      int vc = j - 512;
#pragma unroll
      for (int s = 0; s < 7; s++) SV[(tg * 7 + s) * KS + vc] = f2b(acc[s]);
    }
  }
  __syncthreads();
  // SXW is dead from here on: SQK / SDW alias its region.

  // stage dw5x5 weights + bias into LDS (was per-lane global gather in the conv)
  for (int i = tid; i < 1600; i += 512) SDW[i] = DwcW[i];
  if (tid < 64) SDW[1600 + tid] = DwcB[tid];

  // focus: t^3 renormalized to original L2 norm over C=256, per token (one wave per token)
  const int lane = tid & 63, wvid = tid >> 6;
  for (int t = wvid; t < NTOK; t += 8) {
    float qv[4], ss = 0.f, s6 = 0.f;
#pragma unroll
    for (int m = 0; m < 4; m++) {
      float v = SQ[t * KS + lane + (m << 6)];
      qv[m] = v;
      ss += v * v;
      float c3 = v * v * v;
      s6 += c3 * c3;
    }
#pragma unroll
    for (int off = 1; off < 64; off <<= 1) {
      ss += __shfl_xor(ss, off, 64);
      s6 += __shfl_xor(s6, off, 64);
    }
    float scl = sqrtf(ss) / sqrtf(s6);
#pragma unroll
    for (int m = 0; m < 4; m++) {
      float v = qv[m];
      SQ[t * KS + lane + (m << 6)] = v * v * v * scl;
    }
    float kv[4];
    ss = 0.f;
    s6 = 0.f;
#pragma unroll
    for (int m = 0; m < 4; m++) {
      float v = b2f(SK[t * KS + lane + (m << 6)]);
      kv[m] = v;
      ss += v * v;
      float c3 = v * v * v;
      s6 += c3 * c3;
    }
#pragma unroll
    for (int off = 1; off < 64; off <<= 1) {
      ss += __shfl_xor(ss, off, 64);
      s6 += __shfl_xor(s6, off, 64);
    }
    scl = sqrtf(ss) / sqrtf(s6);
#pragma unroll
    for (int m = 0; m < 4; m++) {
      float v = kv[m];
      SK[t * KS + lane + (m << 6)] = f2b(v * v * v * scl);
    }
  }
  __syncthreads();

  // K column sums for all 4 heads at once (256 channels, fully parallel)
  if (tid < 256) {
    float s = 0.f;
#pragma unroll 7
    for (int j = 0; j < NTOK; j++) s += b2f(SK[j * KS + tid]);
    SKS[tid] = s;
  }
  __syncthreads();

  // z = 1/(q . ksum) for all (head, token) pairs: 196 parallel dots
  for (int e = tid; e < 4 * NTOK; e += 512) {
    int h = e / NTOK, t = e - h * NTOK;
    const float* qp = SQ + t * KS + (h << 6);
    const float* ksp = SKS + (h << 6);
    float s = 0.f;
#pragma unroll 16
    for (int d = 0; d < 64; d++) s = fmaf(qp[d], ksp[d], s);
    SZ[e] = 1.f / (s + 1e-6f);
  }
  // (ordered before first use by the __syncthreads inside the head loop)

  // per-head linear attention (qk path, matches ref branch) + dw5x5 on v
  for (int h = 0; h < 4; h++) {
    const int hb = h << 6;
    // qk[i][jj] = q_i . k_jj  (b128 LDS reads)
    for (int e = tid; e < NTOK * NTOK; e += 512) {
      int i = e / NTOK, jj = e - i * NTOK;
      const float* qp = SQ + i * KS + hb;
      const u16* kp = SK + jj * KS + hb;
      float s = 0.f;
#pragma unroll
      for (int d0 = 0; d0 < 64; d0 += 8) {
        float kf[8];
        unpack8(*(const uint4*)(kp + d0), kf);
        float qf[8];
        load8f(qp + d0, qf);
#pragma unroll
        for (int j2 = 0; j2 < 8; j2++) s = fmaf(qf[j2], kf[j2], s);
      }
      SQK[i * 50 + jj] = s;
    }
    __syncthreads();
    // out[i][d] = z_i * sum_jj qk[i][jj]*v[jj][d]  + dw5x5(v)[i][d]
    // vectorized: each thread owns (token i, 8 consecutive d)
    for (int e = tid; e < NTOK * 8; e += 512) {
      int i = e >> 3, d0 = (e & 7) << 3;
      float acc[8] = {0.f, 0.f, 0.f, 0.f, 0.f, 0.f, 0.f, 0.f};
      const float* qkp = SQK + i * 50;
      for (int jj = 0; jj < NTOK; jj++) {
        float vf[8];
        unpack8(*(const uint4*)(SV + jj * KS + hb + d0), vf);
        float qk = qkp[jj];
#pragma unroll
        for (int j2 = 0; j2 < 8; j2++) acc[j2] = fmaf(qk, vf[j2], acc[j2]);
      }
      float z = SZ[h * NTOK + i];
      int r = i / 7, c = i - r * 7;
      float fm[8];
#pragma unroll
      for (int j2 = 0; j2 < 8; j2++) fm[j2] = SDW[1600 + d0 + j2];
#pragma unroll
      for (int u = 0; u < 5; u++) {
        int rr = r + u - 2;
        if (rr < 0 || rr > 6) continue;
#pragma unroll
        for (int v = 0; v < 5; v++) {
          int cc = c + v - 2;
          if (cc < 0 || cc > 6) continue;
          float vf[8];
          unpack8(*(const uint4*)(SV + (rr * 7 + cc) * KS + hb + d0), vf);
#pragma unroll
          for (int j2 = 0; j2 < 8; j2++) fm[j2] = fmaf(vf[j2], SDW[(d0 + j2) * 25 + u * 5 + v], fm[j2]);
        }
      }
      float o[8];
#pragma unroll
      for (int j2 = 0; j2 < 8; j2++) o[j2] = fmaf(acc[j2], z, fm[j2]);
      *(float4*)(SQ + i * KS + hb + d0) = *(float4*)(o);
      *(float4*)(SQ + i * KS + hb + d0 + 4) = *(float4*)(o + 4);
    }
    __syncthreads();
  }

  // output projection + bias + residual (X is src buffer, Y is dst buffer)
  for (int w = tid; w < 256 * 7; w += 512) {
    int co = w / 7, tg = w - co * 7;
    const float* wrow = PrW + co * 256;
    float acc[7] = {0.f, 0.f, 0.f, 0.f, 0.f, 0.f, 0.f};
    for (int c = 0; c < 256; c += 8) {
      float wf[8];
      load8f(wrow + c, wf);
#pragma unroll
      for (int s = 0; s < 7; s++) {
        float xf[8];
        load8f(SQ + (tg * 7 + s) * KS + c, xf);
        float a = acc[s];
#pragma unroll
        for (int e = 0; e < 8; e++) a = fmaf(wf[e], xf[e], a);
        acc[s] = a;
      }
    }
    float pb = PrB[co];
    int gh = wh * 7 + tg;
    if (gh < 64) {
#pragma unroll
      for (int s = 0; s < 7; s++) {
        int gw = ww * 7 + s;
        if (gw < 64) {
          long addr = bbase + (long)co * 4096 + gh * 64 + gw;
          Y[addr] = acc[s] + pb + X[addr];
        }
      }
    }
  }
}

// ---------- launcher ----------
// Pipeline (D = d_out, A = 128 MiB scratch):
//   1. dwffn0: x -> D     (X2 = X1 + FFN0(X1), X1 on the fly)
//   2. attn:   D -> A     (X3 = X2 + attn(X2))
//   3. dwffn1: A -> D     (out = X4 + FFN1(X4), X4 on the fly)
// A = d_ws if big enough, else reuse x's buffer (x is dead after stage 1; harness
// restores d_in from pristine before every timed launch).
extern "C" void kernel_launch(void* const* d_in, const int* in_sizes, int n_in, void* d_out, int out_size,
                              void* d_ws, size_t ws_size, hipStream_t stream) {
  const float* x = (const float*)d_in[0];
  const float* dw0_w = (const float*)d_in[1];
  const float* dw0_s = (const float*)d_in[2];
  const float* dw0_b = (const float*)d_in[3];
  const float* f0_w1 = (const float*)d_in[4];
  const float* f0_s1 = (const float*)d_in[5];
  const float* f0_b1 = (const float*)d_in[6];
  const float* f0_w2 = (const float*)d_in[7];
  const float* f0_s2 = (const float*)d_in[8];
  const float* f0_b2 = (const float*)d_in[9];
  const float* wq = (const float*)d_in[10];
  const float* wkv = (const float*)d_in[11];
  const float* pos = (const float*)d_in[12];
  const float* scale_p = (const float*)d_in[13];
  const float* dwc_w = (const float*)d_in[14];
  const float* dwc_b = (const float*)d_in[15];
  const float* proj_w = (const float*)d_in[16];
  const float* proj_b = (const float*)d_in[17];
  const float* dw1_w = (const float*)d_in[18];
  const float* dw1_s = (const float*)d_in[19];
  const float* dw1_b = (const float*)d_in[20];
  const float* f1_w1 = (const float*)d_in[21];
  const float* f1_s1 = (const float*)d_in[22];
  const float* f1_b1 = (const float*)d_in[23];
  const float* f1_w2 = (const float*)d_in[24];
  const float* f1_s2 = (const float*)d_in[25];
  const float* f1_b2 = (const float*)d_in[26];

  float* D = (float*)d_out;
  const size_t nbytes = (size_t)out_size * sizeof(float);  // 134,217,728
  float* A = (ws_size >= nbytes) ? (float*)d_ws : (float*)d_in[0];

  (void)hipFuncSetAttribute((const void*)attn_kernel, hipFuncAttributeMaxDynamicSharedMemorySize, SMEM_BYTES);

  // stage 1: X2 = X1 + FFN0(X1),  X1 = x + dwbn0(x)   (x -> D)
  dwffn<<<dim3(128, 32), 256, 0, stream>>>(x, D, dw0_w, dw0_s, dw0_b, f0_w1, f0_s1, f0_b1, f0_w2, f0_s2, f0_b2);
  // stage 2: X3 = X2 + windowed_attn(X2)              (D -> A)
  attn_kernel<<<3200, 512, SMEM_BYTES, stream>>>(D, wq, wkv, pos, scale_p, dwc_w, dwc_b, proj_w, proj_b, A);
  // stage 3: out = X4 + FFN1(X4), X4 = X3 + dwbn1(X3) (A -> D)
  dwffn<<<dim3(128, 32), 256, 0, stream>>>(A, D, dw1_w, dw1_s, dw1_b, f1_w1, f1_s1, f1_b1, f1_w2, f1_s2, f1_b2);
}

// Round 4
// 5181.429 us; speedup vs baseline: 2.7975x; 1.9504x over previous
//
#include <hip/hip_runtime.h>

typedef unsigned short u16;
typedef unsigned int u32;
typedef __attribute__((ext_vector_type(8))) short bf16x8;   // 8 bf16 = 4 VGPRs (MFMA A/B frag)
typedef __attribute__((ext_vector_type(4))) float f32x4;    // MFMA C/D frag

// ---------- bf16 <-> fp32 helpers (LDS staging only; global I/O is fp32) ----------
__device__ __forceinline__ float b2f(u16 v) { return __uint_as_float(((u32)v) << 16); }
__device__ __forceinline__ u16 f2b(float f) {
  u32 u = __float_as_uint(f);
  u32 r = (u + 0x7fffu + ((u >> 16) & 1u)) >> 16;  // RNE
  return (u16)r;
}
__device__ __forceinline__ void unpack8(uint4 u, float* f) {
  f[0] = __uint_as_float(u.x << 16);
  f[1] = __uint_as_float(u.x & 0xffff0000u);
  f[2] = __uint_as_float(u.y << 16);
  f[3] = __uint_as_float(u.y & 0xffff0000u);
  f[4] = __uint_as_float(u.z << 16);
  f[5] = __uint_as_float(u.z & 0xffff0000u);
  f[6] = __uint_as_float(u.w << 16);
  f[7] = __uint_as_float(u.w & 0xffff0000u);
}
__device__ __forceinline__ uint4 pack8(const u16* o) {
  return make_uint4((u32)o[0] | ((u32)o[1] << 16), (u32)o[2] | ((u32)o[3] << 16),
                    (u32)o[4] | ((u32)o[5] << 16), (u32)o[6] | ((u32)o[7] << 16));
}
__device__ __forceinline__ void load8f(const float* p, float* f) {
  *(float4*)(f) = *(const float4*)(p);
  *(float4*)(f + 4) = *(const float4*)(p + 4);
}
// truncate-pack 8 fp32 -> bf16x8 (weights only; error << activation RNE already present)
__device__ __forceinline__ bf16x8 pkbf8(float4 a, float4 b) {
  union { uint4 u; bf16x8 v; } r;
  r.u.x = (__float_as_uint(a.x) >> 16) | (__float_as_uint(a.y) & 0xffff0000u);
  r.u.y = (__float_as_uint(a.z) >> 16) | (__float_as_uint(a.w) & 0xffff0000u);
  r.u.z = (__float_as_uint(b.x) >> 16) | (__float_as_uint(b.y) & 0xffff0000u);
  r.u.w = (__float_as_uint(b.z) >> 16) | (__float_as_uint(b.w) & 0xffff0000u);
  return r.v;
}

// ---------- fused [dw3x3+BN+res] -> [1x1 BN relu] -> [1x1 BN + res], MFMA GEMMs ----------
// Block = 32-pixel chunk (half image row) of one batch, 256 threads (4 waves).
// X1 staged [px][c] bf16 (K-contiguous), hidden [px][h] bf16; both rows XOR-swizzled
// (e ^= (px&7)<<3, u16 units) so 16-row ds_read_b128 B-frags are bank-conflict-free.
// GEMM1: H[512x32] = W1[512x256] @ X1[256x32]  (per wave: 8x2 tiles 16x16, K-loop 8)
// GEMM2: Y[256x32] = W2[256x512] @ H           (per wave: 4x2 tiles,        K-loop 16)
// MFMA frag maps (m89/m91-verified): A row=lane&15,k=(lane>>4)*8+j; D col=lane&15,row=(lane>>4)*4+reg.
// LDS 48 KiB -> 3 blocks/CU; launch_bounds(256,3) caps VGPR to keep them resident.
__global__ __launch_bounds__(256, 3) void dwffn(const float* __restrict__ X, float* __restrict__ Y,
                                                const float* __restrict__ DwW, const float* __restrict__ DwS,
                                                const float* __restrict__ DwB, const float* __restrict__ W1,
                                                const float* __restrict__ S1, const float* __restrict__ B1,
                                                const float* __restrict__ W2, const float* __restrict__ S2,
                                                const float* __restrict__ B2) {
  __shared__ __align__(16) u16 X1s[32 * 256];  // 16 KiB, [px][c] swizzled
  __shared__ __align__(16) u16 Hs[32 * 512];   // 32 KiB, [px][h] swizzled
  const int tid = threadIdx.x;
  const int pix0 = blockIdx.x << 5;                // pixel chunk start in the 4096-pixel plane
  const long zbase = (long)blockIdx.y * 1048576L;  // batch offset (256*4096 elements)
  const int h0 = pix0 >> 6, w0 = pix0 & 63;        // chunk = half of one image row

  // phase A: X1 = x + s*dw3x3(x) + b  -> X1s[px][c] (bf16, swizzled, 4-ch packed writes)
  {
    const int px = tid & 31;
    const int cg = tid >> 5;  // 0..7
    const int w = w0 + px;
    const int sw = (px & 7) << 3;
    for (int it = 0; it < 8; ++it) {
      const int c0 = it * 32 + cg * 4;
      u16 o[4];
#pragma unroll
      for (int cc = 0; cc < 4; ++cc) {
        const int c = c0 + cc;
        const float* xp = X + zbase + (long)c * 4096;
        float acc = 0.f;
#pragma unroll
        for (int u = 0; u < 3; u++) {
          int hh = h0 + u - 1;
          if (hh < 0 || hh > 63) continue;
#pragma unroll
          for (int v = 0; v < 3; v++) {
            int wv2 = w + v - 1;
            if (wv2 < 0 || wv2 > 63) continue;
            acc = fmaf(DwW[c * 9 + u * 3 + v], xp[hh * 64 + wv2], acc);
          }
        }
        o[cc] = f2b(xp[h0 * 64 + w] + fmaf(DwS[c], acc, DwB[c]));
      }
      *(uint2*)&X1s[px * 256 + (c0 ^ sw)] =
          make_uint2((u32)o[0] | ((u32)o[1] << 16), (u32)o[2] | ((u32)o[3] << 16));
    }
  }
  __syncthreads();

  const int lane = tid & 63, wv = tid >> 6;
  const int l15 = lane & 15, lg = lane >> 4;

  // GEMM1: hidden = relu(s1*(W1 @ X1) + b1), wave wv owns hm in [wv*128, wv*128+128)
  {
    f32x4 acc1[8][2];
#pragma unroll
    for (int mt = 0; mt < 8; mt++)
#pragma unroll
      for (int nt = 0; nt < 2; nt++) acc1[mt][nt] = (f32x4){0.f, 0.f, 0.f, 0.f};
    const int hbase = wv * 128;
    for (int kst = 0; kst < 8; ++kst) {
      const int k0 = kst * 32 + lg * 8;
      bf16x8 bq[2];
#pragma unroll
      for (int nt = 0; nt < 2; nt++) {
        const int pxn = nt * 16 + l15;
        bq[nt] = *(const bf16x8*)&X1s[pxn * 256 + (k0 ^ ((pxn & 7) << 3))];
      }
#pragma unroll
      for (int mt = 0; mt < 8; mt++) {
        const float* wr = W1 + (hbase + mt * 16 + l15) * 256 + k0;
        bf16x8 af = pkbf8(*(const float4*)wr, *(const float4*)(wr + 4));
        acc1[mt][0] = __builtin_amdgcn_mfma_f32_16x16x32_bf16(af, bq[0], acc1[mt][0], 0, 0, 0);
        acc1[mt][1] = __builtin_amdgcn_mfma_f32_16x16x32_bf16(af, bq[1], acc1[mt][1], 0, 0, 0);
      }
    }
    // epilogue: bn+relu -> Hs[px][hm] bf16 (4 consecutive hm per lane -> b64 write)
#pragma unroll
    for (int mt = 0; mt < 8; mt++) {
      const int hq = hbase + mt * 16 + lg * 4;
      const float4 s1v = *(const float4*)(S1 + hq);
      const float4 b1v = *(const float4*)(B1 + hq);
#pragma unroll
      for (int nt = 0; nt < 2; nt++) {
        const int pxn = nt * 16 + l15;
        u16 o[4];
        o[0] = f2b(fmaxf(fmaf(s1v.x, acc1[mt][nt][0], b1v.x), 0.f));
        o[1] = f2b(fmaxf(fmaf(s1v.y, acc1[mt][nt][1], b1v.y), 0.f));
        o[2] = f2b(fmaxf(fmaf(s1v.z, acc1[mt][nt][2], b1v.z), 0.f));
        o[3] = f2b(fmaxf(fmaf(s1v.w, acc1[mt][nt][3], b1v.w), 0.f));
        *(uint2*)&Hs[pxn * 512 + (hq ^ ((pxn & 7) << 3))] =
            make_uint2((u32)o[0] | ((u32)o[1] << 16), (u32)o[2] | ((u32)o[3] << 16));
      }
    }
  }
  __syncthreads();

  // GEMM2: out = s2*(W2 @ H) + b2 + X1, wave wv owns co in [wv*64, wv*64+64)
  {
    f32x4 acc2[4][2];
#pragma unroll
    for (int mt = 0; mt < 4; mt++)
#pragma unroll
      for (int nt = 0; nt < 2; nt++) acc2[mt][nt] = (f32x4){0.f, 0.f, 0.f, 0.f};
    const int cbase = wv * 64;
    for (int kst = 0; kst < 16; ++kst) {
      const int k0 = kst * 32 + lg * 8;
      bf16x8 bq[2];
#pragma unroll
      for (int nt = 0; nt < 2; nt++) {
        const int pxn = nt * 16 + l15;
        bq[nt] = *(const bf16x8*)&Hs[pxn * 512 + (k0 ^ ((pxn & 7) << 3))];
      }
#pragma unroll
      for (int mt = 0; mt < 4; mt++) {
        const float* wr = W2 + (cbase + mt * 16 + l15) * 512 + k0;
        bf16x8 af = pkbf8(*(const float4*)wr, *(const float4*)(wr + 4));
        acc2[mt][0] = __builtin_amdgcn_mfma_f32_16x16x32_bf16(af, bq[0], acc2[mt][0], 0, 0, 0);
        acc2[mt][1] = __builtin_amdgcn_mfma_f32_16x16x32_bf16(af, bq[1], acc2[mt][1], 0, 0, 0);
      }
    }
    // epilogue: bn + residual(X1 bf16) -> global
#pragma unroll
    for (int mt = 0; mt < 4; mt++) {
      const int coq = cbase + mt * 16 + lg * 4;
      const float4 s2v = *(const float4*)(S2 + coq);
      const float4 b2v = *(const float4*)(B2 + coq);
#pragma unroll
      for (int nt = 0; nt < 2; nt++) {
        const int pxn = nt * 16 + l15;
        uint2 rv = *(const uint2*)&X1s[pxn * 256 + (coq ^ ((pxn & 7) << 3))];
        float rr0 = __uint_as_float(rv.x << 16);
        float rr1 = __uint_as_float(rv.x & 0xffff0000u);
        float rr2 = __uint_as_float(rv.y << 16);
        float rr3 = __uint_as_float(rv.y & 0xffff0000u);
        float* yp = Y + zbase + (long)coq * 4096 + pix0 + pxn;
        yp[0] = fmaf(s2v.x, acc2[mt][nt][0], b2v.x) + rr0;
        yp[4096] = fmaf(s2v.y, acc2[mt][nt][1], b2v.y) + rr1;
        yp[8192] = fmaf(s2v.z, acc2[mt][nt][2], b2v.z) + rr2;
        yp[12288] = fmaf(s2v.w, acc2[mt][nt][3], b2v.w) + rr3;
      }
    }
  }
}

// ---------- fused windowed focused-linear attention (src != dst) ----------
// one block (512 threads) per window (3200 windows of 49 tokens x 256 ch).
// LDS map (158,064 B total, 1 block/CU, 8 waves/CU):
//   SQ  fp32 49xKS   [0, 51744)
//   SK  bf16 49xKS   [51744, 77616)
//   SV  bf16 49xKS   [77616, 103488)
//   SXW fp32 49xKS   [103488, 155232)  -- dead after projections; then:
//     SQK fp32 49x50   [103488, 113288)  (alias)
//     SDW fp32 1664    [113288, 119944)  (dwc 5x5 weights + bias, alias)
//   SSC fp32 256, SKS fp32 256, SZ fp32 196
#define NTOK 49
#define KS 264  // LDS token stride (elements); 16B-aligned rows
#define OFF_SK (NTOK * KS * 4)              // SQ: fp32 49xKS
#define OFF_SV (OFF_SK + NTOK * KS * 2)     // SK: bf16
#define OFF_SXW (OFF_SV + NTOK * KS * 2)    // SV: bf16
#define OFF_SQK (OFF_SXW)                   // alias: SQK over dead SXW
#define OFF_SDW (OFF_SXW + NTOK * 50 * 4 + 88)  // 113288: dwc weights, 16B aligned
#define OFF_SSC (OFF_SXW + NTOK * KS * 4)   // 155232
#define OFF_SKS (OFF_SSC + 256 * 4)
#define OFF_SZ (OFF_SKS + 256 * 4)
#define SMEM_BYTES (OFF_SZ + 4 * NTOK * 4)  // 158,064 B (< 160 KiB)

__global__ __launch_bounds__(512) void attn_kernel(const float* __restrict__ X, const float* __restrict__ Wq,
                                                   const float* __restrict__ Wkv, const float* __restrict__ Pos,
                                                   const float* __restrict__ ScaleP, const float* __restrict__ DwcW,
                                                   const float* __restrict__ DwcB, const float* __restrict__ PrW,
                                                   const float* __restrict__ PrB, float* __restrict__ Y) {
  extern __shared__ char smem[];
  float* SQ = (float*)(smem);
  u16* SK = (u16*)(smem + OFF_SK);
  u16* SV = (u16*)(smem + OFF_SV);
  float* SXW = (float*)(smem + OFF_SXW);
  float* SQK = (float*)(smem + OFF_SQK);
  float* SDW = (float*)(smem + OFF_SDW);
  float* SSC = (float*)(smem + OFF_SSC);
  float* SKS = (float*)(smem + OFF_SKS);
  float* SZ = (float*)(smem + OFF_SZ);

  const int tid = threadIdx.x;
  const int wi = blockIdx.x;
  const int b = wi / 100;
  const int rem = wi - b * 100;
  const int wh = rem / 10, ww = rem - (rem / 10) * 10;
  const long bbase = (long)b * (256L * 4096L);

  // softplus(scale_p) per channel
  if (tid < 256) SSC[tid] = log1pf(expf(ScaleP[tid]));

  // gather window (zero-padded) into LDS, token-major, fp32
  for (int i = tid; i < NTOK * 256; i += 512) {
    int c = i / NTOK, t = i - c * NTOK;
    int r = t / 7, cc = t - r * 7;
    int gh = wh * 7 + r, gw = ww * 7 + cc;
    float v = 0.f;
    if (gh < 64 && gw < 64) v = X[bbase + (long)c * 4096 + gh * 64 + gw];
    SXW[t * KS + c] = v;
  }
  __syncthreads();

  // q / kv projections (fp32 LDS reads, no unpack in the inner loop)
  for (int w = tid; w < 768 * 7; w += 512) {
    int j = w / 7, tg = w - j * 7;
    const float* wrow = (j < 256) ? (Wq + j * 256) : (Wkv + (j - 256) * 256);
    float acc[7] = {0.f, 0.f, 0.f, 0.f, 0.f, 0.f, 0.f};
    for (int c = 0; c < 256; c += 8) {
      float wf[8];
      load8f(wrow + c, wf);
#pragma unroll
      for (int s = 0; s < 7; s++) {
        float xf[8];
        load8f(SXW + (tg * 7 + s) * KS + c, xf);
        float a = acc[s];
#pragma unroll
        for (int e = 0; e < 8; e++) a = fmaf(wf[e], xf[e], a);
        acc[s] = a;
      }
    }
    if (j < 256) {
      float sc = SSC[j];
#pragma unroll
      for (int s = 0; s < 7; s++) {
        int t = tg * 7 + s;
        SQ[t * KS + j] = (fmaxf(acc[s], 0.f) + 1e-6f) / sc;
      }
    } else if (j < 512) {
      int kc = j - 256;
      float sc = SSC[kc];
#pragma unroll
      for (int s = 0; s < 7; s++) {
        int t = tg * 7 + s;
        float v = acc[s] + Pos[t * 256 + kc];
        SK[t * KS + kc] = f2b((fmaxf(v, 0.f) + 1e-6f) / sc);
      }
    } else {
      int vc = j - 512;
#pragma unroll
      for (int s = 0; s < 7; s++) SV[(tg * 7 + s) * KS + vc] = f2b(acc[s]);
    }
  }
  __syncthreads();
  // SXW is dead from here on: SQK / SDW alias its region.

  // stage dw5x5 weights + bias into LDS (was per-lane global gather in the conv)
  for (int i = tid; i < 1600; i += 512) SDW[i] = DwcW[i];
  if (tid < 64) SDW[1600 + tid] = DwcB[tid];

  // focus: t^3 renormalized to original L2 norm over C=256, per token (one wave per token)
  const int lane = tid & 63, wvid = tid >> 6;
  for (int t = wvid; t < NTOK; t += 8) {
    float qv[4], ss = 0.f, s6 = 0.f;
#pragma unroll
    for (int m = 0; m < 4; m++) {
      float v = SQ[t * KS + lane + (m << 6)];
      qv[m] = v;
      ss += v * v;
      float c3 = v * v * v;
      s6 += c3 * c3;
    }
#pragma unroll
    for (int off = 1; off < 64; off <<= 1) {
      ss += __shfl_xor(ss, off, 64);
      s6 += __shfl_xor(s6, off, 64);
    }
    float scl = sqrtf(ss) / sqrtf(s6);
#pragma unroll
    for (int m = 0; m < 4; m++) {
      float v = qv[m];
      SQ[t * KS + lane + (m << 6)] = v * v * v * scl;
    }
    float kv[4];
    ss = 0.f;
    s6 = 0.f;
#pragma unroll
    for (int m = 0; m < 4; m++) {
      float v = b2f(SK[t * KS + lane + (m << 6)]);
      kv[m] = v;
      ss += v * v;
      float c3 = v * v * v;
      s6 += c3 * c3;
    }
#pragma unroll
    for (int off = 1; off < 64; off <<= 1) {
      ss += __shfl_xor(ss, off, 64);
      s6 += __shfl_xor(s6, off, 64);
    }
    scl = sqrtf(ss) / sqrtf(s6);
#pragma unroll
    for (int m = 0; m < 4; m++) {
      float v = kv[m];
      SK[t * KS + lane + (m << 6)] = f2b(v * v * v * scl);
    }
  }
  __syncthreads();

  // K column sums for all 4 heads at once (256 channels, fully parallel)
  if (tid < 256) {
    float s = 0.f;
#pragma unroll 7
    for (int j = 0; j < NTOK; j++) s += b2f(SK[j * KS + tid]);
    SKS[tid] = s;
  }
  __syncthreads();

  // z = 1/(q . ksum) for all (head, token) pairs: 196 parallel dots
  for (int e = tid; e < 4 * NTOK; e += 512) {
    int h = e / NTOK, t = e - h * NTOK;
    const float* qp = SQ + t * KS + (h << 6);
    const float* ksp = SKS + (h << 6);
    float s = 0.f;
#pragma unroll 16
    for (int d = 0; d < 64; d++) s = fmaf(qp[d], ksp[d], s);
    SZ[e] = 1.f / (s + 1e-6f);
  }
  // (ordered before first use by the __syncthreads inside the head loop)

  // per-head linear attention (qk path, matches ref branch) + dw5x5 on v
  for (int h = 0; h < 4; h++) {
    const int hb = h << 6;
    // qk[i][jj] = q_i . k_jj  (b128 LDS reads)
    for (int e = tid; e < NTOK * NTOK; e += 512) {
      int i = e / NTOK, jj = e - i * NTOK;
      const float* qp = SQ + i * KS + hb;
      const u16* kp = SK + jj * KS + hb;
      float s = 0.f;
#pragma unroll
      for (int d0 = 0; d0 < 64; d0 += 8) {
        float kf[8];
        unpack8(*(const uint4*)(kp + d0), kf);
        float qf[8];
        load8f(qp + d0, qf);
#pragma unroll
        for (int j2 = 0; j2 < 8; j2++) s = fmaf(qf[j2], kf[j2], s);
      }
      SQK[i * 50 + jj] = s;
    }
    __syncthreads();
    // out[i][d] = z_i * sum_jj qk[i][jj]*v[jj][d]  + dw5x5(v)[i][d]
    // vectorized: each thread owns (token i, 8 consecutive d)
    for (int e = tid; e < NTOK * 8; e += 512) {
      int i = e >> 3, d0 = (e & 7) << 3;
      float acc[8] = {0.f, 0.f, 0.f, 0.f, 0.f, 0.f, 0.f, 0.f};
      const float* qkp = SQK + i * 50;
      for (int jj = 0; jj < NTOK; jj++) {
        float vf[8];
        unpack8(*(const uint4*)(SV + jj * KS + hb + d0), vf);
        float qk = qkp[jj];
#pragma unroll
        for (int j2 = 0; j2 < 8; j2++) acc[j2] = fmaf(qk, vf[j2], acc[j2]);
      }
      float z = SZ[h * NTOK + i];
      int r = i / 7, c = i - r * 7;
      float fm[8];
#pragma unroll
      for (int j2 = 0; j2 < 8; j2++) fm[j2] = SDW[1600 + d0 + j2];
#pragma unroll
      for (int u = 0; u < 5; u++) {
        int rr = r + u - 2;
        if (rr < 0 || rr > 6) continue;
#pragma unroll
        for (int v = 0; v < 5; v++) {
          int cc = c + v - 2;
          if (cc < 0 || cc > 6) continue;
          float vf[8];
          unpack8(*(const uint4*)(SV + (rr * 7 + cc) * KS + hb + d0), vf);
#pragma unroll
          for (int j2 = 0; j2 < 8; j2++) fm[j2] = fmaf(vf[j2], SDW[(d0 + j2) * 25 + u * 5 + v], fm[j2]);
        }
      }
      float o[8];
#pragma unroll
      for (int j2 = 0; j2 < 8; j2++) o[j2] = fmaf(acc[j2], z, fm[j2]);
      *(float4*)(SQ + i * KS + hb + d0) = *(float4*)(o);
      *(float4*)(SQ + i * KS + hb + d0 + 4) = *(float4*)(o + 4);
    }
    __syncthreads();
  }

  // output projection + bias + residual (X is src buffer, Y is dst buffer)
  for (int w = tid; w < 256 * 7; w += 512) {
    int co = w / 7, tg = w - co * 7;
    const float* wrow = PrW + co * 256;
    float acc[7] = {0.f, 0.f, 0.f, 0.f, 0.f, 0.f, 0.f};
    for (int c = 0; c < 256; c += 8) {
      float wf[8];
      load8f(wrow + c, wf);
#pragma unroll
      for (int s = 0; s < 7; s++) {
        float xf[8];
        load8f(SQ + (tg * 7 + s) * KS + c, xf);
        float a = acc[s];
#pragma unroll
        for (int e = 0; e < 8; e++) a = fmaf(wf[e], xf[e], a);
        acc[s] = a;
      }
    }
    float pb = PrB[co];
    int gh = wh * 7 + tg;
    if (gh < 64) {
#pragma unroll
      for (int s = 0; s < 7; s++) {
        int gw = ww * 7 + s;
        if (gw < 64) {
          long addr = bbase + (long)co * 4096 + gh * 64 + gw;
          Y[addr] = acc[s] + pb + X[addr];
        }
      }
    }
  }
}

// ---------- launcher ----------
// Pipeline (D = d_out, A = 128 MiB scratch):
//   1. dwffn0: x -> D     (X2 = X1 + FFN0(X1), X1 on the fly)
//   2. attn:   D -> A     (X3 = X2 + attn(X2))
//   3. dwffn1: A -> D     (out = X4 + FFN1(X4), X4 on the fly)
// A = d_ws if big enough, else reuse x's buffer (x is dead after stage 1; harness
// restores d_in from pristine before every timed launch).
extern "C" void kernel_launch(void* const* d_in, const int* in_sizes, int n_in, void* d_out, int out_size,
                              void* d_ws, size_t ws_size, hipStream_t stream) {
  const float* x = (const float*)d_in[0];
  const float* dw0_w = (const float*)d_in[1];
  const float* dw0_s = (const float*)d_in[2];
  const float* dw0_b = (const float*)d_in[3];
  const float* f0_w1 = (const float*)d_in[4];
  const float* f0_s1 = (const float*)d_in[5];
  const float* f0_b1 = (const float*)d_in[6];
  const float* f0_w2 = (const float*)d_in[7];
  const float* f0_s2 = (const float*)d_in[8];
  const float* f0_b2 = (const float*)d_in[9];
  const float* wq = (const float*)d_in[10];
  const float* wkv = (const float*)d_in[11];
  const float* pos = (const float*)d_in[12];
  const float* scale_p = (const float*)d_in[13];
  const float* dwc_w = (const float*)d_in[14];
  const float* dwc_b = (const float*)d_in[15];
  const float* proj_w = (const float*)d_in[16];
  const float* proj_b = (const float*)d_in[17];
  const float* dw1_w = (const float*)d_in[18];
  const float* dw1_s = (const float*)d_in[19];
  const float* dw1_b = (const float*)d_in[20];
  const float* f1_w1 = (const float*)d_in[21];
  const float* f1_s1 = (const float*)d_in[22];
  const float* f1_b1 = (const float*)d_in[23];
  const float* f1_w2 = (const float*)d_in[24];
  const float* f1_s2 = (const float*)d_in[25];
  const float* f1_b2 = (const float*)d_in[26];

  float* D = (float*)d_out;
  const size_t nbytes = (size_t)out_size * sizeof(float);  // 134,217,728
  float* A = (ws_size >= nbytes) ? (float*)d_ws : (float*)d_in[0];

  (void)hipFuncSetAttribute((const void*)attn_kernel, hipFuncAttributeMaxDynamicSharedMemorySize, SMEM_BYTES);

  // stage 1: X2 = X1 + FFN0(X1),  X1 = x + dwbn0(x)   (x -> D)
  dwffn<<<dim3(128, 32), 256, 0, stream>>>(x, D, dw0_w, dw0_s, dw0_b, f0_w1, f0_s1, f0_b1, f0_w2, f0_s2, f0_b2);
  // stage 2: X3 = X2 + windowed_attn(X2)              (D -> A)
  attn_kernel<<<3200, 512, SMEM_BYTES, stream>>>(D, wq, wkv, pos, scale_p, dwc_w, dwc_b, proj_w, proj_b, A);
  // stage 3: out = X4 + FFN1(X4), X4 = X3 + dwbn1(X3) (A -> D)
  dwffn<<<dim3(128, 32), 256, 0, stream>>>(A, D, dw1_w, dw1_s, dw1_b, f1_w1, f1_s1, f1_b1, f1_w2, f1_s2, f1_b2);
}

// Round 6
// 3526.748 us; speedup vs baseline: 4.1101x; 1.4692x over previous
//
#include <hip/hip_runtime.h>

typedef unsigned short u16;
typedef unsigned int u32;
typedef __attribute__((ext_vector_type(8))) short bf16x8;   // 8 bf16 = 4 VGPRs (MFMA A/B frag)
typedef __attribute__((ext_vector_type(4))) float f32x4;    // MFMA C/D frag

// ---------- bf16 <-> fp32 helpers (LDS staging only; global I/O is fp32) ----------
__device__ __forceinline__ float b2f(u16 v) { return __uint_as_float(((u32)v) << 16); }
__device__ __forceinline__ u16 f2b(float f) {
  u32 u = __float_as_uint(f);
  u32 r = (u + 0x7fffu + ((u >> 16) & 1u)) >> 16;  // RNE
  return (u16)r;
}
__device__ __forceinline__ void unpack8(uint4 u, float* f) {
  f[0] = __uint_as_float(u.x << 16);
  f[1] = __uint_as_float(u.x & 0xffff0000u);
  f[2] = __uint_as_float(u.y << 16);
  f[3] = __uint_as_float(u.y & 0xffff0000u);
  f[4] = __uint_as_float(u.z << 16);
  f[5] = __uint_as_float(u.z & 0xffff0000u);
  f[6] = __uint_as_float(u.w << 16);
  f[7] = __uint_as_float(u.w & 0xffff0000u);
}
__device__ __forceinline__ uint4 pack8(const u16* o) {
  return make_uint4((u32)o[0] | ((u32)o[1] << 16), (u32)o[2] | ((u32)o[3] << 16),
                    (u32)o[4] | ((u32)o[5] << 16), (u32)o[6] | ((u32)o[7] << 16));
}
__device__ __forceinline__ void load8f(const float* p, float* f) {
  *(float4*)(f) = *(const float4*)(p);
  *(float4*)(f + 4) = *(const float4*)(p + 4);
}
// truncate-pack 8 fp32 -> bf16x8 (weights only; error << activation RNE already present)
__device__ __forceinline__ bf16x8 pkbf8(float4 a, float4 b) {
  union { uint4 u; bf16x8 v; } r;
  r.u.x = (__float_as_uint(a.x) >> 16) | (__float_as_uint(a.y) & 0xffff0000u);
  r.u.y = (__float_as_uint(a.z) >> 16) | (__float_as_uint(a.w) & 0xffff0000u);
  r.u.z = (__float_as_uint(b.x) >> 16) | (__float_as_uint(b.y) & 0xffff0000u);
  r.u.w = (__float_as_uint(b.z) >> 16) | (__float_as_uint(b.w) & 0xffff0000u);
  return r.v;
}

// ---------- fused [dw3x3+BN+res] -> [1x1 BN relu] -> [1x1 BN + res], MFMA GEMMs ----------
// (unchanged from round 3 — verified: 3.5 ms -> ~0.75 ms)
__global__ __launch_bounds__(256, 3) void dwffn(const float* __restrict__ X, float* __restrict__ Y,
                                                const float* __restrict__ DwW, const float* __restrict__ DwS,
                                                const float* __restrict__ DwB, const float* __restrict__ W1,
                                                const float* __restrict__ S1, const float* __restrict__ B1,
                                                const float* __restrict__ W2, const float* __restrict__ S2,
                                                const float* __restrict__ B2) {
  __shared__ __align__(16) u16 X1s[32 * 256];  // 16 KiB, [px][c] swizzled
  __shared__ __align__(16) u16 Hs[32 * 512];   // 32 KiB, [px][h] swizzled
  const int tid = threadIdx.x;
  const int pix0 = blockIdx.x << 5;
  const long zbase = (long)blockIdx.y * 1048576L;
  const int h0 = pix0 >> 6, w0 = pix0 & 63;

  // phase A: X1 = x + s*dw3x3(x) + b  -> X1s[px][c] (bf16, swizzled)
  {
    const int px = tid & 31;
    const int cg = tid >> 5;  // 0..7
    const int w = w0 + px;
    const int sw = (px & 7) << 3;
    for (int it = 0; it < 8; ++it) {
      const int c0 = it * 32 + cg * 4;
      u16 o[4];
#pragma unroll
      for (int cc = 0; cc < 4; ++cc) {
        const int c = c0 + cc;
        const float* xp = X + zbase + (long)c * 4096;
        float acc = 0.f;
#pragma unroll
        for (int u = 0; u < 3; u++) {
          int hh = h0 + u - 1;
          if (hh < 0 || hh > 63) continue;
#pragma unroll
          for (int v = 0; v < 3; v++) {
            int wv2 = w + v - 1;
            if (wv2 < 0 || wv2 > 63) continue;
            acc = fmaf(DwW[c * 9 + u * 3 + v], xp[hh * 64 + wv2], acc);
          }
        }
        o[cc] = f2b(xp[h0 * 64 + w] + fmaf(DwS[c], acc, DwB[c]));
      }
      *(uint2*)&X1s[px * 256 + (c0 ^ sw)] =
          make_uint2((u32)o[0] | ((u32)o[1] << 16), (u32)o[2] | ((u32)o[3] << 16));
    }
  }
  __syncthreads();

  const int lane = tid & 63, wv = tid >> 6;
  const int l15 = lane & 15, lg = lane >> 4;

  // GEMM1: hidden = relu(s1*(W1 @ X1) + b1)
  {
    f32x4 acc1[8][2];
#pragma unroll
    for (int mt = 0; mt < 8; mt++)
#pragma unroll
      for (int nt = 0; nt < 2; nt++) acc1[mt][nt] = (f32x4){0.f, 0.f, 0.f, 0.f};
    const int hbase = wv * 128;
    for (int kst = 0; kst < 8; ++kst) {
      const int k0 = kst * 32 + lg * 8;
      bf16x8 bq[2];
#pragma unroll
      for (int nt = 0; nt < 2; nt++) {
        const int pxn = nt * 16 + l15;
        bq[nt] = *(const bf16x8*)&X1s[pxn * 256 + (k0 ^ ((pxn & 7) << 3))];
      }
#pragma unroll
      for (int mt = 0; mt < 8; mt++) {
        const float* wr = W1 + (hbase + mt * 16 + l15) * 256 + k0;
        bf16x8 af = pkbf8(*(const float4*)wr, *(const float4*)(wr + 4));
        acc1[mt][0] = __builtin_amdgcn_mfma_f32_16x16x32_bf16(af, bq[0], acc1[mt][0], 0, 0, 0);
        acc1[mt][1] = __builtin_amdgcn_mfma_f32_16x16x32_bf16(af, bq[1], acc1[mt][1], 0, 0, 0);
      }
    }
#pragma unroll
    for (int mt = 0; mt < 8; mt++) {
      const int hq = hbase + mt * 16 + lg * 4;
      const float4 s1v = *(const float4*)(S1 + hq);
      const float4 b1v = *(const float4*)(B1 + hq);
#pragma unroll
      for (int nt = 0; nt < 2; nt++) {
        const int pxn = nt * 16 + l15;
        u16 o[4];
        o[0] = f2b(fmaxf(fmaf(s1v.x, acc1[mt][nt][0], b1v.x), 0.f));
        o[1] = f2b(fmaxf(fmaf(s1v.y, acc1[mt][nt][1], b1v.y), 0.f));
        o[2] = f2b(fmaxf(fmaf(s1v.z, acc1[mt][nt][2], b1v.z), 0.f));
        o[3] = f2b(fmaxf(fmaf(s1v.w, acc1[mt][nt][3], b1v.w), 0.f));
        *(uint2*)&Hs[pxn * 512 + (hq ^ ((pxn & 7) << 3))] =
            make_uint2((u32)o[0] | ((u32)o[1] << 16), (u32)o[2] | ((u32)o[3] << 16));
      }
    }
  }
  __syncthreads();

  // GEMM2: out = s2*(W2 @ H) + b2 + X1
  {
    f32x4 acc2[4][2];
#pragma unroll
    for (int mt = 0; mt < 4; mt++)
#pragma unroll
      for (int nt = 0; nt < 2; nt++) acc2[mt][nt] = (f32x4){0.f, 0.f, 0.f, 0.f};
    const int cbase = wv * 64;
    for (int kst = 0; kst < 16; ++kst) {
      const int k0 = kst * 32 + lg * 8;
      bf16x8 bq[2];
#pragma unroll
      for (int nt = 0; nt < 2; nt++) {
        const int pxn = nt * 16 + l15;
        bq[nt] = *(const bf16x8*)&Hs[pxn * 512 + (k0 ^ ((pxn & 7) << 3))];
      }
#pragma unroll
      for (int mt = 0; mt < 4; mt++) {
        const float* wr = W2 + (cbase + mt * 16 + l15) * 512 + k0;
        bf16x8 af = pkbf8(*(const float4*)wr, *(const float4*)(wr + 4));
        acc2[mt][0] = __builtin_amdgcn_mfma_f32_16x16x32_bf16(af, bq[0], acc2[mt][0], 0, 0, 0);
        acc2[mt][1] = __builtin_amdgcn_mfma_f32_16x16x32_bf16(af, bq[1], acc2[mt][1], 0, 0, 0);
      }
    }
#pragma unroll
    for (int mt = 0; mt < 4; mt++) {
      const int coq = cbase + mt * 16 + lg * 4;
      const float4 s2v = *(const float4*)(S2 + coq);
      const float4 b2v = *(const float4*)(B2 + coq);
#pragma unroll
      for (int nt = 0; nt < 2; nt++) {
        const int pxn = nt * 16 + l15;
        uint2 rv = *(const uint2*)&X1s[pxn * 256 + (coq ^ ((pxn & 7) << 3))];
        float rr0 = __uint_as_float(rv.x << 16);
        float rr1 = __uint_as_float(rv.x & 0xffff0000u);
        float rr2 = __uint_as_float(rv.y << 16);
        float rr3 = __uint_as_float(rv.y & 0xffff0000u);
        float* yp = Y + zbase + (long)coq * 4096 + pix0 + pxn;
        yp[0] = fmaf(s2v.x, acc2[mt][nt][0], b2v.x) + rr0;
        yp[4096] = fmaf(s2v.y, acc2[mt][nt][1], b2v.y) + rr1;
        yp[8192] = fmaf(s2v.z, acc2[mt][nt][2], b2v.z) + rr2;
        yp[12288] = fmaf(s2v.w, acc2[mt][nt][3], b2v.w) + rr3;
      }
    }
  }
}

// ---------- fused windowed focused-linear attention, MFMA projections (src != dst) ----------
// one block (512 threads = 8 waves) per window (3200 windows of 49 tokens x 256 ch).
// GEMM-P: [q;k;v][768 x 64tok] = [Wq;Wkv] @ XW   (per wave 6 M-tiles x 4 N-tiles, K-loop 8)
// GEMM-O: Y[256 x 64tok]       = PrW @ attn-out  (per wave 2 M-tiles x 4 N-tiles, K-loop 8)
// XW bf16 [64tok][256c] XOR-swizzled (tok&7)<<3; reused for attn-out (dead after GEMM-P).
// NOTE: dwc weights/bias are PER-HEAD-CHANNEL (0..63, shared across heads) — index with d0+j2, NOT hb+d0+j2.
// LDS map (155,552 B, 16B-aligned regions):
#define NTOK 49
#define KS 264                               // SQ/SK/SV token stride (fp32/bf16 elems)
#define OFF_XW 0                             // bf16 64x256 = 32768
#define OFF_SQ 32768                         // fp32 49xKS  = 51744 -> 84512
#define OFF_SK 84512                         // bf16 49xKS  = 25872 -> 110384
#define OFF_SV 110384                        // bf16 49xKS  = 25872 -> 136256
#define OFF_SQK 136256                       // fp32 49x50  = 9800  -> 146056(+8 pad)
#define OFF_SDW 146064                       // fp32 1664   = 6656  -> 152720
#define OFF_SSC 152720                       // fp32 256 -> 153744
#define OFF_SKS 153744                       // fp32 256 -> 154768
#define OFF_SZ 154768                        // fp32 196 -> 155552
#define SMEM_BYTES 155552

__global__ __launch_bounds__(512) void attn_kernel(const float* __restrict__ X, const float* __restrict__ Wq,
                                                   const float* __restrict__ Wkv, const float* __restrict__ Pos,
                                                   const float* __restrict__ ScaleP, const float* __restrict__ DwcW,
                                                   const float* __restrict__ DwcB, const float* __restrict__ PrW,
                                                   const float* __restrict__ PrB, float* __restrict__ Y) {
  extern __shared__ char smem[];
  u16* XW = (u16*)(smem + OFF_XW);
  float* SQ = (float*)(smem + OFF_SQ);
  u16* SK = (u16*)(smem + OFF_SK);
  u16* SV = (u16*)(smem + OFF_SV);
  float* SQK = (float*)(smem + OFF_SQK);
  float* SDW = (float*)(smem + OFF_SDW);
  float* SSC = (float*)(smem + OFF_SSC);
  float* SKS = (float*)(smem + OFF_SKS);
  float* SZ = (float*)(smem + OFF_SZ);

  const int tid = threadIdx.x;
  const int wi = blockIdx.x;
  const int b = wi / 100;
  const int rem = wi - b * 100;
  const int wh = rem / 10, ww = rem - (rem / 10) * 10;
  const long bbase = (long)b * (256L * 4096L);

  // softplus(scale_p); dwc weights+bias -> LDS
  if (tid < 256) SSC[tid] = log1pf(expf(ScaleP[tid]));
  for (int i = tid; i < 1600; i += 512) SDW[i] = DwcW[i];
  if (tid < 64) SDW[1600 + tid] = DwcB[tid];

  // gather window -> XW bf16 [64tok][256c] swizzled, zero-padded (tok>=49 and OOB pixels)
  for (int u = tid; u < 64 * 32; u += 512) {
    const int cg = u >> 6, t = u & 63;
    const int c0 = cg << 3;
    u16 o[8] = {0, 0, 0, 0, 0, 0, 0, 0};
    if (t < NTOK) {
      const int r = t / 7, cc = t - r * 7;
      const int gh = wh * 7 + r, gw = ww * 7 + cc;
      if (gh < 64 && gw < 64) {
        const float* xp = X + bbase + gh * 64 + gw;
#pragma unroll
        for (int e = 0; e < 8; e++) o[e] = f2b(xp[(long)(c0 + e) * 4096]);
      }
    }
    *(uint4*)&XW[t * 256 + (c0 ^ ((t & 7) << 3))] = pack8(o);
  }
  __syncthreads();

  const int lane = tid & 63, wvid = tid >> 6;
  const int l15 = lane & 15, lg = lane >> 4;

  // GEMM-P: wave owns M-tiles {wv+8*mt} of [Wq(0..15) | K(16..31) | V(32..47)]
  {
    const float* wr_base[6];
    int tile[6];
#pragma unroll
    for (int mt = 0; mt < 6; mt++) {
      const int tl = wvid + (mt << 3);
      tile[mt] = tl;
      const int row = (tl << 4) + l15;
      wr_base[mt] = (row < 256) ? (Wq + row * 256) : (Wkv + (row - 256) * 256);
    }
    f32x4 acc[6][4];
#pragma unroll
    for (int mt = 0; mt < 6; mt++)
#pragma unroll
      for (int nt = 0; nt < 4; nt++) acc[mt][nt] = (f32x4){0.f, 0.f, 0.f, 0.f};
    for (int kst = 0; kst < 8; ++kst) {
      const int k0 = kst * 32 + lg * 8;
      bf16x8 bq[4];
#pragma unroll
      for (int nt = 0; nt < 4; nt++) {
        const int tkn = (nt << 4) + l15;
        bq[nt] = *(const bf16x8*)&XW[tkn * 256 + (k0 ^ ((tkn & 7) << 3))];
      }
#pragma unroll
      for (int mt = 0; mt < 6; mt++) {
        bf16x8 af = pkbf8(*(const float4*)(wr_base[mt] + k0), *(const float4*)(wr_base[mt] + k0 + 4));
#pragma unroll
        for (int nt = 0; nt < 4; nt++)
          acc[mt][nt] = __builtin_amdgcn_mfma_f32_16x16x32_bf16(af, bq[nt], acc[mt][nt], 0, 0, 0);
      }
    }
    // epilogues: q -> SQ fp32; k -> (+pos, relu, /sc) SK bf16; v -> SV bf16
#pragma unroll
    for (int mt = 0; mt < 6; mt++) {
      const int tl = tile[mt];
#pragma unroll
      for (int nt = 0; nt < 4; nt++) {
        const int tkn = (nt << 4) + l15;
        if (tkn >= NTOK) continue;
        if (tl < 16) {
          const int jq = (tl << 4) + (lg << 2);
          const float4 sc = *(const float4*)(SSC + jq);
          float4 o;
          o.x = (fmaxf(acc[mt][nt][0], 0.f) + 1e-6f) / sc.x;
          o.y = (fmaxf(acc[mt][nt][1], 0.f) + 1e-6f) / sc.y;
          o.z = (fmaxf(acc[mt][nt][2], 0.f) + 1e-6f) / sc.z;
          o.w = (fmaxf(acc[mt][nt][3], 0.f) + 1e-6f) / sc.w;
          *(float4*)&SQ[tkn * KS + jq] = o;
        } else if (tl < 32) {
          const int kc = ((tl - 16) << 4) + (lg << 2);
          const float4 sc = *(const float4*)(SSC + kc);
          const float4 pp = *(const float4*)(Pos + tkn * 256 + kc);
          u16 o[4];
          o[0] = f2b((fmaxf(acc[mt][nt][0] + pp.x, 0.f) + 1e-6f) / sc.x);
          o[1] = f2b((fmaxf(acc[mt][nt][1] + pp.y, 0.f) + 1e-6f) / sc.y);
          o[2] = f2b((fmaxf(acc[mt][nt][2] + pp.z, 0.f) + 1e-6f) / sc.z);
          o[3] = f2b((fmaxf(acc[mt][nt][3] + pp.w, 0.f) + 1e-6f) / sc.w);
          *(uint2*)&SK[tkn * KS + kc] = make_uint2((u32)o[0] | ((u32)o[1] << 16), (u32)o[2] | ((u32)o[3] << 16));
        } else {
          const int vc = ((tl - 32) << 4) + (lg << 2);
          u16 o[4];
          o[0] = f2b(acc[mt][nt][0]);
          o[1] = f2b(acc[mt][nt][1]);
          o[2] = f2b(acc[mt][nt][2]);
          o[3] = f2b(acc[mt][nt][3]);
          *(uint2*)&SV[tkn * KS + vc] = make_uint2((u32)o[0] | ((u32)o[1] << 16), (u32)o[2] | ((u32)o[3] << 16));
        }
      }
    }
  }
  __syncthreads();

  // focus: t^3 renormalized to original L2 norm over C=256, one wave per token
  for (int t = wvid; t < NTOK; t += 8) {
    float qv[4], ss = 0.f, s6 = 0.f;
#pragma unroll
    for (int m = 0; m < 4; m++) {
      float v = SQ[t * KS + lane + (m << 6)];
      qv[m] = v;
      ss += v * v;
      float c3 = v * v * v;
      s6 += c3 * c3;
    }
#pragma unroll
    for (int off = 1; off < 64; off <<= 1) {
      ss += __shfl_xor(ss, off, 64);
      s6 += __shfl_xor(s6, off, 64);
    }
    float scl = sqrtf(ss) / sqrtf(s6);
#pragma unroll
    for (int m = 0; m < 4; m++) {
      float v = qv[m];
      SQ[t * KS + lane + (m << 6)] = v * v * v * scl;
    }
    float kv[4];
    ss = 0.f;
    s6 = 0.f;
#pragma unroll
    for (int m = 0; m < 4; m++) {
      float v = b2f(SK[t * KS + lane + (m << 6)]);
      kv[m] = v;
      ss += v * v;
      float c3 = v * v * v;
      s6 += c3 * c3;
    }
#pragma unroll
    for (int off = 1; off < 64; off <<= 1) {
      ss += __shfl_xor(ss, off, 64);
      s6 += __shfl_xor(s6, off, 64);
    }
    scl = sqrtf(ss) / sqrtf(s6);
#pragma unroll
    for (int m = 0; m < 4; m++) {
      float v = kv[m];
      SK[t * KS + lane + (m << 6)] = f2b(v * v * v * scl);
    }
  }
  __syncthreads();

  // K column sums (all 4 heads at once)
  if (tid < 256) {
    float s = 0.f;
#pragma unroll 7
    for (int j = 0; j < NTOK; j++) s += b2f(SK[j * KS + tid]);
    SKS[tid] = s;
  }
  __syncthreads();

  // z = 1/(q . ksum) for all (head, token) pairs
  for (int e = tid; e < 4 * NTOK; e += 512) {
    int h = e / NTOK, t = e - h * NTOK;
    const float* qp = SQ + t * KS + (h << 6);
    const float* ksp = SKS + (h << 6);
    float s = 0.f;
#pragma unroll 16
    for (int d = 0; d < 64; d++) s = fmaf(qp[d], ksp[d], s);
    SZ[e] = 1.f / (s + 1e-6f);
  }
  // (SZ ordered before first use by the __syncthreads inside the head loop)

  // per-head linear attention (qk path) + dw5x5 on v; attn-out -> XW (bf16, swizzled)
  for (int h = 0; h < 4; h++) {
    const int hb = h << 6;
    for (int e = tid; e < NTOK * NTOK; e += 512) {
      int i = e / NTOK, jj = e - i * NTOK;
      const float* qp = SQ + i * KS + hb;
      const u16* kp = SK + jj * KS + hb;
      float s = 0.f;
#pragma unroll
      for (int d0 = 0; d0 < 64; d0 += 8) {
        float kf[8];
        unpack8(*(const uint4*)(kp + d0), kf);
        float qf[8];
        load8f(qp + d0, qf);
#pragma unroll
        for (int j2 = 0; j2 < 8; j2++) s = fmaf(qf[j2], kf[j2], s);
      }
      SQK[i * 50 + jj] = s;
    }
    __syncthreads();
    for (int e = tid; e < NTOK * 8; e += 512) {
      int i = e >> 3, d0 = (e & 7) << 3;
      float acc[8] = {0.f, 0.f, 0.f, 0.f, 0.f, 0.f, 0.f, 0.f};
      const float* qkp = SQK + i * 50;
      for (int jj = 0; jj < NTOK; jj++) {
        float vf[8];
        unpack8(*(const uint4*)(SV + jj * KS + hb + d0), vf);
        float qk = qkp[jj];
#pragma unroll
        for (int j2 = 0; j2 < 8; j2++) acc[j2] = fmaf(qk, vf[j2], acc[j2]);
      }
      float z = SZ[h * NTOK + i];
      int r = i / 7, c = i - r * 7;
      float fm[8];
#pragma unroll
      for (int j2 = 0; j2 < 8; j2++) fm[j2] = SDW[1600 + d0 + j2];  // per-head channel d0+j2 (shared across heads)
#pragma unroll
      for (int u = 0; u < 5; u++) {
        int rr = r + u - 2;
        if (rr < 0 || rr > 6) continue;
#pragma unroll
        for (int v = 0; v < 5; v++) {
          int cc = c + v - 2;
          if (cc < 0 || cc > 6) continue;
          float vf[8];
          unpack8(*(const uint4*)(SV + (rr * 7 + cc) * KS + hb + d0), vf);
#pragma unroll
          for (int j2 = 0; j2 < 8; j2++) fm[j2] = fmaf(vf[j2], SDW[(d0 + j2) * 25 + u * 5 + v], fm[j2]);  // no hb!
        }
      }
      u16 ob[8];
#pragma unroll
      for (int j2 = 0; j2 < 8; j2++) ob[j2] = f2b(fmaf(acc[j2], z, fm[j2]));
      *(uint4*)&XW[i * 256 + ((hb + d0) ^ ((i & 7) << 3))] = pack8(ob);
    }
    __syncthreads();
  }

  // GEMM-O: out = PrW @ attn-out + bias + residual; wave owns co in [wv*32, wv*32+32)
  {
    f32x4 acc[2][4];
#pragma unroll
    for (int mt = 0; mt < 2; mt++)
#pragma unroll
      for (int nt = 0; nt < 4; nt++) acc[mt][nt] = (f32x4){0.f, 0.f, 0.f, 0.f};
    const int cbase = wvid * 32;
    for (int kst = 0; kst < 8; ++kst) {
      const int k0 = kst * 32 + lg * 8;
      bf16x8 bq[4];
#pragma unroll
      for (int nt = 0; nt < 4; nt++) {
        const int tkn = (nt << 4) + l15;
        bq[nt] = *(const bf16x8*)&XW[tkn * 256 + (k0 ^ ((tkn & 7) << 3))];
      }
#pragma unroll
      for (int mt = 0; mt < 2; mt++) {
        const float* wr = PrW + (cbase + mt * 16 + l15) * 256 + k0;
        bf16x8 af = pkbf8(*(const float4*)wr, *(const float4*)(wr + 4));
#pragma unroll
        for (int nt = 0; nt < 4; nt++)
          acc[mt][nt] = __builtin_amdgcn_mfma_f32_16x16x32_bf16(af, bq[nt], acc[mt][nt], 0, 0, 0);
      }
    }
#pragma unroll
    for (int mt = 0; mt < 2; mt++) {
      const int coq = cbase + mt * 16 + (lg << 2);
      const float4 pbv = *(const float4*)(PrB + coq);
#pragma unroll
      for (int nt = 0; nt < 4; nt++) {
        const int tkn = (nt << 4) + l15;
        if (tkn >= NTOK) continue;
        const int r = tkn / 7, cc = tkn - r * 7;
        const int gh = wh * 7 + r, gw = ww * 7 + cc;
        if (gh < 64 && gw < 64) {
          const long addr = bbase + (long)coq * 4096 + gh * 64 + gw;
          Y[addr] = acc[mt][nt][0] + pbv.x + X[addr];
          Y[addr + 4096] = acc[mt][nt][1] + pbv.y + X[addr + 4096];
          Y[addr + 8192] = acc[mt][nt][2] + pbv.z + X[addr + 8192];
          Y[addr + 12288] = acc[mt][nt][3] + pbv.w + X[addr + 12288];
        }
      }
    }
  }
}

// ---------- launcher ----------
// Pipeline (D = d_out, A = 128 MiB scratch):
//   1. dwffn0: x -> D
//   2. attn:   D -> A
//   3. dwffn1: A -> D
extern "C" void kernel_launch(void* const* d_in, const int* in_sizes, int n_in, void* d_out, int out_size,
                              void* d_ws, size_t ws_size, hipStream_t stream) {
  const float* x = (const float*)d_in[0];
  const float* dw0_w = (const float*)d_in[1];
  const float* dw0_s = (const float*)d_in[2];
  const float* dw0_b = (const float*)d_in[3];
  const float* f0_w1 = (const float*)d_in[4];
  const float* f0_s1 = (const float*)d_in[5];
  const float* f0_b1 = (const float*)d_in[6];
  const float* f0_w2 = (const float*)d_in[7];
  const float* f0_s2 = (const float*)d_in[8];
  const float* f0_b2 = (const float*)d_in[9];
  const float* wq = (const float*)d_in[10];
  const float* wkv = (const float*)d_in[11];
  const float* pos = (const float*)d_in[12];
  const float* scale_p = (const float*)d_in[13];
  const float* dwc_w = (const float*)d_in[14];
  const float* dwc_b = (const float*)d_in[15];
  const float* proj_w = (const float*)d_in[16];
  const float* proj_b = (const float*)d_in[17];
  const float* dw1_w = (const float*)d_in[18];
  const float* dw1_s = (const float*)d_in[19];
  const float* dw1_b = (const float*)d_in[20];
  const float* f1_w1 = (const float*)d_in[21];
  const float* f1_s1 = (const float*)d_in[22];
  const float* f1_b1 = (const float*)d_in[23];
  const float* f1_w2 = (const float*)d_in[24];
  const float* f1_s2 = (const float*)d_in[25];
  const float* f1_b2 = (const float*)d_in[26];

  float* D = (float*)d_out;
  const size_t nbytes = (size_t)out_size * sizeof(float);  // 134,217,728
  float* A = (ws_size >= nbytes) ? (float*)d_ws : (float*)d_in[0];

  (void)hipFuncSetAttribute((const void*)attn_kernel, hipFuncAttributeMaxDynamicSharedMemorySize, SMEM_BYTES);

  dwffn<<<dim3(128, 32), 256, 0, stream>>>(x, D, dw0_w, dw0_s, dw0_b, f0_w1, f0_s1, f0_b1, f0_w2, f0_s2, f0_b2);
  attn_kernel<<<3200, 512, SMEM_BYTES, stream>>>(D, wq, wkv, pos, scale_p, dwc_w, dwc_b, proj_w, proj_b, A);
  dwffn<<<dim3(128, 32), 256, 0, stream>>>(A, D, dw1_w, dw1_s, dw1_b, f1_w1, f1_s1, f1_b1, f1_w2, f1_s2, f1_b2);
}

// Round 9
// 2956.942 us; speedup vs baseline: 4.9021x; 1.1927x over previous
//
#include <hip/hip_runtime.h>

typedef unsigned short u16;
typedef unsigned int u32;
typedef __attribute__((ext_vector_type(8))) short bf16x8;   // 8 bf16 = 4 VGPRs (MFMA A/B frag)
typedef __attribute__((ext_vector_type(4))) float f32x4;    // MFMA C/D frag

// ---------- bf16 <-> fp32 helpers (LDS staging only; global I/O is fp32) ----------
__device__ __forceinline__ float b2f(u16 v) { return __uint_as_float(((u32)v) << 16); }
__device__ __forceinline__ u16 f2b(float f) {
  u32 u = __float_as_uint(f);
  u32 r = (u + 0x7fffu + ((u >> 16) & 1u)) >> 16;  // RNE
  return (u16)r;
}
__device__ __forceinline__ void unpack8(uint4 u, float* f) {
  f[0] = __uint_as_float(u.x << 16);
  f[1] = __uint_as_float(u.x & 0xffff0000u);
  f[2] = __uint_as_float(u.y << 16);
  f[3] = __uint_as_float(u.y & 0xffff0000u);
  f[4] = __uint_as_float(u.z << 16);
  f[5] = __uint_as_float(u.z & 0xffff0000u);
  f[6] = __uint_as_float(u.w << 16);
  f[7] = __uint_as_float(u.w & 0xffff0000u);
}
__device__ __forceinline__ uint4 pack8(const u16* o) {
  return make_uint4((u32)o[0] | ((u32)o[1] << 16), (u32)o[2] | ((u32)o[3] << 16),
                    (u32)o[4] | ((u32)o[5] << 16), (u32)o[6] | ((u32)o[7] << 16));
}
// truncate-pack 8 fp32 -> bf16x8 (weights only; error << activation RNE already present)
__device__ __forceinline__ bf16x8 pkbf8(float4 a, float4 b) {
  union { uint4 u; bf16x8 v; } r;
  r.u.x = (__float_as_uint(a.x) >> 16) | (__float_as_uint(a.y) & 0xffff0000u);
  r.u.y = (__float_as_uint(a.z) >> 16) | (__float_as_uint(a.w) & 0xffff0000u);
  r.u.z = (__float_as_uint(b.x) >> 16) | (__float_as_uint(b.y) & 0xffff0000u);
  r.u.w = (__float_as_uint(b.z) >> 16) | (__float_as_uint(b.w) & 0xffff0000u);
  return r.v;
}

// ---------- fused [dw3x3+BN+res] -> [1x1 BN relu] -> [1x1 BN + res], MFMA GEMMs ----------
// (unchanged — verified ~0.75 ms)
__global__ __launch_bounds__(256, 3) void dwffn(const float* __restrict__ X, float* __restrict__ Y,
                                                const float* __restrict__ DwW, const float* __restrict__ DwS,
                                                const float* __restrict__ DwB, const float* __restrict__ W1,
                                                const float* __restrict__ S1, const float* __restrict__ B1,
                                                const float* __restrict__ W2, const float* __restrict__ S2,
                                                const float* __restrict__ B2) {
  __shared__ __align__(16) u16 X1s[32 * 256];  // 16 KiB, [px][c] swizzled
  __shared__ __align__(16) u16 Hs[32 * 512];   // 32 KiB, [px][h] swizzled
  const int tid = threadIdx.x;
  const int pix0 = blockIdx.x << 5;
  const long zbase = (long)blockIdx.y * 1048576L;
  const int h0 = pix0 >> 6, w0 = pix0 & 63;

  // phase A: X1 = x + s*dw3x3(x) + b  -> X1s[px][c] (bf16, swizzled)
  {
    const int px = tid & 31;
    const int cg = tid >> 5;  // 0..7
    const int w = w0 + px;
    const int sw = (px & 7) << 3;
    for (int it = 0; it < 8; ++it) {
      const int c0 = it * 32 + cg * 4;
      u16 o[4];
#pragma unroll
      for (int cc = 0; cc < 4; ++cc) {
        const int c = c0 + cc;
        const float* xp = X + zbase + (long)c * 4096;
        float acc = 0.f;
#pragma unroll
        for (int u = 0; u < 3; u++) {
          int hh = h0 + u - 1;
          if (hh < 0 || hh > 63) continue;
#pragma unroll
          for (int v = 0; v < 3; v++) {
            int wv2 = w + v - 1;
            if (wv2 < 0 || wv2 > 63) continue;
            acc = fmaf(DwW[c * 9 + u * 3 + v], xp[hh * 64 + wv2], acc);
          }
        }
        o[cc] = f2b(xp[h0 * 64 + w] + fmaf(DwS[c], acc, DwB[c]));
      }
      *(uint2*)&X1s[px * 256 + (c0 ^ sw)] =
          make_uint2((u32)o[0] | ((u32)o[1] << 16), (u32)o[2] | ((u32)o[3] << 16));
    }
  }
  __syncthreads();

  const int lane = tid & 63, wv = tid >> 6;
  const int l15 = lane & 15, lg = lane >> 4;

  // GEMM1: hidden = relu(s1*(W1 @ X1) + b1)
  {
    f32x4 acc1[8][2];
#pragma unroll
    for (int mt = 0; mt < 8; mt++)
#pragma unroll
      for (int nt = 0; nt < 2; nt++) acc1[mt][nt] = (f32x4){0.f, 0.f, 0.f, 0.f};
    const int hbase = wv * 128;
    for (int kst = 0; kst < 8; ++kst) {
      const int k0 = kst * 32 + lg * 8;
      bf16x8 bq[2];
#pragma unroll
      for (int nt = 0; nt < 2; nt++) {
        const int pxn = nt * 16 + l15;
        bq[nt] = *(const bf16x8*)&X1s[pxn * 256 + (k0 ^ ((pxn & 7) << 3))];
      }
#pragma unroll
      for (int mt = 0; mt < 8; mt++) {
        const float* wr = W1 + (hbase + mt * 16 + l15) * 256 + k0;
        bf16x8 af = pkbf8(*(const float4*)wr, *(const float4*)(wr + 4));
        acc1[mt][0] = __builtin_amdgcn_mfma_f32_16x16x32_bf16(af, bq[0], acc1[mt][0], 0, 0, 0);
        acc1[mt][1] = __builtin_amdgcn_mfma_f32_16x16x32_bf16(af, bq[1], acc1[mt][1], 0, 0, 0);
      }
    }
#pragma unroll
    for (int mt = 0; mt < 8; mt++) {
      const int hq = hbase + mt * 16 + lg * 4;
      const float4 s1v = *(const float4*)(S1 + hq);
      const float4 b1v = *(const float4*)(B1 + hq);
#pragma unroll
      for (int nt = 0; nt < 2; nt++) {
        const int pxn = nt * 16 + l15;
        u16 o[4];
        o[0] = f2b(fmaxf(fmaf(s1v.x, acc1[mt][nt][0], b1v.x), 0.f));
        o[1] = f2b(fmaxf(fmaf(s1v.y, acc1[mt][nt][1], b1v.y), 0.f));
        o[2] = f2b(fmaxf(fmaf(s1v.z, acc1[mt][nt][2], b1v.z), 0.f));
        o[3] = f2b(fmaxf(fmaf(s1v.w, acc1[mt][nt][3], b1v.w), 0.f));
        *(uint2*)&Hs[pxn * 512 + (hq ^ ((pxn & 7) << 3))] =
            make_uint2((u32)o[0] | ((u32)o[1] << 16), (u32)o[2] | ((u32)o[3] << 16));
      }
    }
  }
  __syncthreads();

  // GEMM2: out = s2*(W2 @ H) + b2 + X1
  {
    f32x4 acc2[4][2];
#pragma unroll
    for (int mt = 0; mt < 4; mt++)
#pragma unroll
      for (int nt = 0; nt < 2; nt++) acc2[mt][nt] = (f32x4){0.f, 0.f, 0.f, 0.f};
    const int cbase = wv * 64;
    for (int kst = 0; kst < 16; ++kst) {
      const int k0 = kst * 32 + lg * 8;
      bf16x8 bq[2];
#pragma unroll
      for (int nt = 0; nt < 2; nt++) {
        const int pxn = nt * 16 + l15;
        bq[nt] = *(const bf16x8*)&Hs[pxn * 512 + (k0 ^ ((pxn & 7) << 3))];
      }
#pragma unroll
      for (int mt = 0; mt < 4; mt++) {
        const float* wr = W2 + (cbase + mt * 16 + l15) * 512 + k0;
        bf16x8 af = pkbf8(*(const float4*)wr, *(const float4*)(wr + 4));
        acc2[mt][0] = __builtin_amdgcn_mfma_f32_16x16x32_bf16(af, bq[0], acc2[mt][0], 0, 0, 0);
        acc2[mt][1] = __builtin_amdgcn_mfma_f32_16x16x32_bf16(af, bq[1], acc2[mt][1], 0, 0, 0);
      }
    }
#pragma unroll
    for (int mt = 0; mt < 4; mt++) {
      const int coq = cbase + mt * 16 + lg * 4;
      const float4 s2v = *(const float4*)(S2 + coq);
      const float4 b2v = *(const float4*)(B2 + coq);
#pragma unroll
      for (int nt = 0; nt < 2; nt++) {
        const int pxn = nt * 16 + l15;
        uint2 rv = *(const uint2*)&X1s[pxn * 256 + (coq ^ ((pxn & 7) << 3))];
        float rr0 = __uint_as_float(rv.x << 16);
        float rr1 = __uint_as_float(rv.x & 0xffff0000u);
        float rr2 = __uint_as_float(rv.y << 16);
        float rr3 = __uint_as_float(rv.y & 0xffff0000u);
        float* yp = Y + zbase + (long)coq * 4096 + pix0 + pxn;
        yp[0] = fmaf(s2v.x, acc2[mt][nt][0], b2v.x) + rr0;
        yp[4096] = fmaf(s2v.y, acc2[mt][nt][1], b2v.y) + rr1;
        yp[8192] = fmaf(s2v.z, acc2[mt][nt][2], b2v.z) + rr2;
        yp[12288] = fmaf(s2v.w, acc2[mt][nt][3], b2v.w) + rr3;
      }
    }
  }
}

// ---------- fused windowed focused-linear attention, full-MFMA (src != dst) ----------
// one block (512 threads = 8 waves) per window (3200 windows, 49 tok padded to 64, 256 ch).
// All matmul phases on MFMA (C = A_rowmajor · B_rowmajor^T, K-contiguous frags):
//   GEMM-P: [q;k;v][768x64] = [Wq;Wkv] @ XW      (192 MFMA/wave)
//   qk:     QK[h][64x64]    = Q · K^T  (K=d 64)  ( 16 MFMA/wave) -> bf16
//   PV:     y[64x256]       = QK · SVT^T (K=j 64)( 16 MFMA/wave), z fused in epilogue
//   GEMM-O: out[256x64]     = PrW @ attn-out     ( 64 MFMA/wave)
// z[h][i] = 1/(row-sum_j QK[h][i][j] + 1e-6)  (== q·ksum, SKS phase eliminated)
// dw5x5 on v: d-major per-thread (thread = (channel, token-half)), RMW-add into attn-out.
// NOTE: dwc weights/bias indexed by HEAD-channel (d & 63), shared across the 4 heads!
// LDS regions (all bf16 [row][col] with col ^= (row&7)<<3 swizzle; 139,776 B):
#define NTOK 49
#define AOFF_XW 0        // [64 tok][256 ch] gather input; later QK[4][64][64] (dead after GEMM-P)
#define AOFF_SQB 32768   // [64 tok][256 ch] q; later attn-out (dead after qk)
#define AOFF_SKB 65536   // [64 tok][256 ch] k
#define AOFF_SVT 98304   // [256 ch][64 tok] v, d-major
#define AOFF_SDW 131072  // fp32 1600 dwc w + 64 bias = 6656 B
#define AOFF_SSC 137728  // fp32 256 softplus
#define AOFF_SZ 138752   // fp32 256 z (h*64+i)
#define SMEM_BYTES 139776

__global__ __launch_bounds__(512) void attn_kernel(const float* __restrict__ X, const float* __restrict__ Wq,
                                                   const float* __restrict__ Wkv, const float* __restrict__ Pos,
                                                   const float* __restrict__ ScaleP, const float* __restrict__ DwcW,
                                                   const float* __restrict__ DwcB, const float* __restrict__ PrW,
                                                   const float* __restrict__ PrB, float* __restrict__ Y) {
  extern __shared__ char smem[];
  u16* XW = (u16*)(smem + AOFF_XW);    // gather; later QK
  u16* QKB = (u16*)(smem + AOFF_XW);   // alias
  u16* SQB = (u16*)(smem + AOFF_SQB);  // q; later attn-out
  u16* AO = (u16*)(smem + AOFF_SQB);   // alias
  u16* SKB = (u16*)(smem + AOFF_SKB);
  u16* SVT = (u16*)(smem + AOFF_SVT);
  float* SDW = (float*)(smem + AOFF_SDW);
  float* SSC = (float*)(smem + AOFF_SSC);
  float* SZ = (float*)(smem + AOFF_SZ);

  const int tid = threadIdx.x;
  const int wi = blockIdx.x;
  const int b = wi / 100;
  const int rem = wi - b * 100;
  const int wh = rem / 10, ww = rem - (rem / 10) * 10;
  const long bbase = (long)b * (256L * 4096L);

  // softplus(scale_p); dwc weights+bias -> LDS
  if (tid < 256) SSC[tid] = log1pf(expf(ScaleP[tid]));
  for (int i = tid; i < 1600; i += 512) SDW[i] = DwcW[i];
  if (tid < 64) SDW[1600 + tid] = DwcB[tid];

  // zero SQB/SKB/SVT entirely (pad rows/cols MUST be 0 — MFMA pads multiply by them).
  // 3 regions x 32768 B = 98304 B = 6144 uint4.
  {
    const uint4 z4 = make_uint4(0, 0, 0, 0);
    uint4* zb = (uint4*)(smem + AOFF_SQB);
    for (int e = tid; e < 6144; e += 512) zb[e] = z4;
  }

  // gather window -> XW bf16 [64tok][256c] swizzled, zero-padded
  for (int u = tid; u < 64 * 32; u += 512) {
    const int cg = u >> 6, t = u & 63;
    const int c0 = cg << 3;
    u16 o[8] = {0, 0, 0, 0, 0, 0, 0, 0};
    if (t < NTOK) {
      const int r = t / 7, cc = t - r * 7;
      const int gh = wh * 7 + r, gw = ww * 7 + cc;
      if (gh < 64 && gw < 64) {
        const float* xp = X + bbase + gh * 64 + gw;
#pragma unroll
        for (int e = 0; e < 8; e++) o[e] = f2b(xp[(long)(c0 + e) * 4096]);
      }
    }
    *(uint4*)&XW[t * 256 + (c0 ^ ((t & 7) << 3))] = pack8(o);
  }
  __syncthreads();

  const int lane = tid & 63, wvid = tid >> 6;
  const int l15 = lane & 15, lg = lane >> 4;

  // GEMM-P: wave owns M-tiles {wvid+8*mt} of [Wq(0..15) | K(16..31) | V(32..47)]
  {
    const float* wr_base[6];
    int tile[6];
#pragma unroll
    for (int mt = 0; mt < 6; mt++) {
      const int tl = wvid + (mt << 3);
      tile[mt] = tl;
      const int row = (tl << 4) + l15;
      wr_base[mt] = (row < 256) ? (Wq + row * 256) : (Wkv + (row - 256) * 256);
    }
    f32x4 acc[6][4];
#pragma unroll
    for (int mt = 0; mt < 6; mt++)
#pragma unroll
      for (int nt = 0; nt < 4; nt++) acc[mt][nt] = (f32x4){0.f, 0.f, 0.f, 0.f};
    for (int kst = 0; kst < 8; ++kst) {
      const int k0 = kst * 32 + lg * 8;
      bf16x8 bq[4];
#pragma unroll
      for (int nt = 0; nt < 4; nt++) {
        const int tkn = (nt << 4) + l15;
        bq[nt] = *(const bf16x8*)&XW[tkn * 256 + (k0 ^ ((tkn & 7) << 3))];
      }
#pragma unroll
      for (int mt = 0; mt < 6; mt++) {
        bf16x8 af = pkbf8(*(const float4*)(wr_base[mt] + k0), *(const float4*)(wr_base[mt] + k0 + 4));
#pragma unroll
        for (int nt = 0; nt < 4; nt++)
          acc[mt][nt] = __builtin_amdgcn_mfma_f32_16x16x32_bf16(af, bq[nt], acc[mt][nt], 0, 0, 0);
      }
    }
    // epilogues: q -> SQB bf16; k -> (+pos, relu, /sc) SKB bf16; v -> SVT d-major bf16
#pragma unroll
    for (int mt = 0; mt < 6; mt++) {
      const int tl = tile[mt];
#pragma unroll
      for (int nt = 0; nt < 4; nt++) {
        const int tkn = (nt << 4) + l15;
        if (tkn >= NTOK) continue;
        const int sw = (tkn & 7) << 3;
        if (tl < 16) {
          const int jq = (tl << 4) + (lg << 2);
          const float4 sc = *(const float4*)(SSC + jq);
          u16 o[4];
          o[0] = f2b((fmaxf(acc[mt][nt][0], 0.f) + 1e-6f) / sc.x);
          o[1] = f2b((fmaxf(acc[mt][nt][1], 0.f) + 1e-6f) / sc.y);
          o[2] = f2b((fmaxf(acc[mt][nt][2], 0.f) + 1e-6f) / sc.z);
          o[3] = f2b((fmaxf(acc[mt][nt][3], 0.f) + 1e-6f) / sc.w);
          *(uint2*)&SQB[tkn * 256 + (jq ^ sw)] = make_uint2((u32)o[0] | ((u32)o[1] << 16), (u32)o[2] | ((u32)o[3] << 16));
        } else if (tl < 32) {
          const int kc = ((tl - 16) << 4) + (lg << 2);
          const float4 sc = *(const float4*)(SSC + kc);
          const float4 pp = *(const float4*)(Pos + tkn * 256 + kc);
          u16 o[4];
          o[0] = f2b((fmaxf(acc[mt][nt][0] + pp.x, 0.f) + 1e-6f) / sc.x);
          o[1] = f2b((fmaxf(acc[mt][nt][1] + pp.y, 0.f) + 1e-6f) / sc.y);
          o[2] = f2b((fmaxf(acc[mt][nt][2] + pp.z, 0.f) + 1e-6f) / sc.z);
          o[3] = f2b((fmaxf(acc[mt][nt][3] + pp.w, 0.f) + 1e-6f) / sc.w);
          *(uint2*)&SKB[tkn * 256 + (kc ^ sw)] = make_uint2((u32)o[0] | ((u32)o[1] << 16), (u32)o[2] | ((u32)o[3] << 16));
        } else {
          const int vc = ((tl - 32) << 4) + (lg << 2);
#pragma unroll
          for (int cc = 0; cc < 4; cc++) {
            const int d = vc + cc;
            SVT[d * 64 + (tkn ^ ((d & 7) << 3))] = f2b(acc[mt][nt][cc]);
          }
        }
      }
    }
  }
  __syncthreads();

  // focus: t^3 renorm to original L2 over C=256 (bf16 in/out), one wave per token
  for (int t = wvid; t < NTOK; t += 8) {
    const int sw = (t & 7) << 3;
    float qv[4], ss = 0.f, s6 = 0.f;
#pragma unroll
    for (int m = 0; m < 4; m++) {
      float v = b2f(SQB[t * 256 + ((lane + (m << 6)) ^ sw)]);
      qv[m] = v;
      ss += v * v;
      float c3 = v * v * v;
      s6 += c3 * c3;
    }
#pragma unroll
    for (int off = 1; off < 64; off <<= 1) {
      ss += __shfl_xor(ss, off, 64);
      s6 += __shfl_xor(s6, off, 64);
    }
    float scl = sqrtf(ss) / sqrtf(s6);
#pragma unroll
    for (int m = 0; m < 4; m++) {
      float v = qv[m];
      SQB[t * 256 + ((lane + (m << 6)) ^ sw)] = f2b(v * v * v * scl);
    }
    float kv[4];
    ss = 0.f;
    s6 = 0.f;
#pragma unroll
    for (int m = 0; m < 4; m++) {
      float v = b2f(SKB[t * 256 + ((lane + (m << 6)) ^ sw)]);
      kv[m] = v;
      ss += v * v;
      float c3 = v * v * v;
      s6 += c3 * c3;
    }
#pragma unroll
    for (int off = 1; off < 64; off <<= 1) {
      ss += __shfl_xor(ss, off, 64);
      s6 += __shfl_xor(s6, off, 64);
    }
    scl = sqrtf(ss) / sqrtf(s6);
#pragma unroll
    for (int m = 0; m < 4; m++) {
      float v = kv[m];
      SKB[t * 256 + ((lane + (m << 6)) ^ sw)] = f2b(v * v * v * scl);
    }
  }
  __syncthreads();

  // qk MFMA: QK[h][i][j] = q_i . k_j over d=64; 64 tile-jobs (h,ti,tj) across 8 waves
  for (int jj = 0; jj < 8; ++jj) {
    const int job = (jj << 3) + wvid;
    const int h = job >> 4;
    const int r2 = job & 15;
    const int ti = r2 >> 2, tj = r2 & 3;
    const int hb = h << 6;
    f32x4 a = (f32x4){0.f, 0.f, 0.f, 0.f};
#pragma unroll
    for (int kst = 0; kst < 2; ++kst) {
      const int k0 = hb + kst * 32 + lg * 8;
      const int irow = ti * 16 + l15;
      const int jrow = tj * 16 + l15;
      bf16x8 qa = *(const bf16x8*)&SQB[irow * 256 + (k0 ^ ((irow & 7) << 3))];
      bf16x8 kb = *(const bf16x8*)&SKB[jrow * 256 + (k0 ^ ((jrow & 7) << 3))];
      a = __builtin_amdgcn_mfma_f32_16x16x32_bf16(qa, kb, a, 0, 0, 0);
    }
#pragma unroll
    for (int reg = 0; reg < 4; ++reg) {
      const int i = ti * 16 + lg * 4 + reg, j = tj * 16 + l15;
      QKB[((h << 6) + i) * 64 + (j ^ ((i & 7) << 3))] = f2b(a[reg]);
    }
  }
  __syncthreads();

  // z[h][i] = 1/(row-sum QK + 1e-6); swizzle permutes within the row, sum is order-free
  if (tid < 256) {
    const uint4* rowp = (const uint4*)&QKB[tid * 64];
    float s = 0.f;
#pragma unroll
    for (int k = 0; k < 8; k++) {
      uint4 uu = rowp[(k + tid) & 7];  // staggered start: avoid all-lanes-same-bank
      float f[8];
      unpack8(uu, f);
#pragma unroll
      for (int e = 0; e < 8; e++) s += f[e];
    }
    SZ[tid] = 1.f / (s + 1e-6f);
  }
  __syncthreads();

  // PV MFMA: y[i][d] = z_i * sum_j QK[i][j] V[j][d]; 64 tile-jobs (ti, d-tile) across 8 waves
  for (int jj = 0; jj < 8; ++jj) {
    const int job = (jj << 3) + wvid;
    const int ti = job >> 4;
    const int dt = job & 15;
    const int h = dt >> 2;
    f32x4 a = (f32x4){0.f, 0.f, 0.f, 0.f};
#pragma unroll
    for (int kst = 0; kst < 2; ++kst) {
      const int j0 = kst * 32 + lg * 8;
      const int irow = ti * 16 + l15;
      const int drow = (dt << 4) + l15;
      bf16x8 qk = *(const bf16x8*)&QKB[((h << 6) + irow) * 64 + (j0 ^ ((irow & 7) << 3))];
      bf16x8 vt = *(const bf16x8*)&SVT[drow * 64 + (j0 ^ ((drow & 7) << 3))];
      a = __builtin_amdgcn_mfma_f32_16x16x32_bf16(qk, vt, a, 0, 0, 0);
    }
#pragma unroll
    for (int reg = 0; reg < 4; ++reg) {
      const int i = ti * 16 + lg * 4 + reg;
      const int d = (dt << 4) + l15;
      const float z = SZ[(h << 6) + i];
      AO[i * 256 + (d ^ ((i & 7) << 3))] = f2b(a[reg] * z);
    }
  }
  __syncthreads();

  // dw5x5 on v, d-major: thread = (channel d, token-half); RMW-add into attn-out.
  // dwc filter/bias are PER-HEAD-CHANNEL: index with dch = d & 63 (shared across heads).
  {
    const int d = tid >> 1, half = tid & 1;
    const int dch = d & 63;
    const float bias = SDW[1600 + dch];
    const int swd = (d & 7) << 3;
    const u16* vrow = SVT + d * 64;
    const float* wrow = SDW + dch * 25;
    const int rlo = half ? 4 : 0, rhi = half ? 7 : 4;
    for (int r = rlo; r < rhi; ++r) {
      for (int c = 0; c < 7; ++c) {
        float fm = bias;
#pragma unroll
        for (int u = 0; u < 5; u++) {
          const int rr = r + u - 2;
          if (rr < 0 || rr > 6) continue;
#pragma unroll
          for (int v = 0; v < 5; v++) {
            const int cc = c + v - 2;
            if (cc < 0 || cc > 6) continue;
            fm = fmaf(b2f(vrow[(rr * 7 + cc) ^ swd]), wrow[u * 5 + v], fm);
          }
        }
        const int t = r * 7 + c;
        const int idx = t * 256 + (d ^ ((t & 7) << 3));
        AO[idx] = f2b(b2f(AO[idx]) + fm);
      }
    }
  }
  __syncthreads();

  // GEMM-O: out = PrW @ attn-out + bias + residual; wave owns co in [wvid*32, +32)
  {
    f32x4 acc[2][4];
#pragma unroll
    for (int mt = 0; mt < 2; mt++)
#pragma unroll
      for (int nt = 0; nt < 4; nt++) acc[mt][nt] = (f32x4){0.f, 0.f, 0.f, 0.f};
    const int cbase = wvid * 32;
    for (int kst = 0; kst < 8; ++kst) {
      const int k0 = kst * 32 + lg * 8;
      bf16x8 bq[4];
#pragma unroll
      for (int nt = 0; nt < 4; nt++) {
        const int tkn = (nt << 4) + l15;
        bq[nt] = *(const bf16x8*)&AO[tkn * 256 + (k0 ^ ((tkn & 7) << 3))];
      }
#pragma unroll
      for (int mt = 0; mt < 2; mt++) {
        const float* wr = PrW + (cbase + mt * 16 + l15) * 256 + k0;
        bf16x8 af = pkbf8(*(const float4*)wr, *(const float4*)(wr + 4));
#pragma unroll
        for (int nt = 0; nt < 4; nt++)
          acc[mt][nt] = __builtin_amdgcn_mfma_f32_16x16x32_bf16(af, bq[nt], acc[mt][nt], 0, 0, 0);
      }
    }
#pragma unroll
    for (int mt = 0; mt < 2; mt++) {
      const int coq = cbase + mt * 16 + (lg << 2);
      const float4 pbv = *(const float4*)(PrB + coq);
#pragma unroll
      for (int nt = 0; nt < 4; nt++) {
        const int tkn = (nt << 4) + l15;
        if (tkn >= NTOK) continue;
        const int r = tkn / 7, cc = tkn - r * 7;
        const int gh = wh * 7 + r, gw = ww * 7 + cc;
        if (gh < 64 && gw < 64) {
          const long addr = bbase + (long)coq * 4096 + gh * 64 + gw;
          Y[addr] = acc[mt][nt][0] + pbv.x + X[addr];
          Y[addr + 4096] = acc[mt][nt][1] + pbv.y + X[addr + 4096];
          Y[addr + 8192] = acc[mt][nt][2] + pbv.z + X[addr + 8192];
          Y[addr + 12288] = acc[mt][nt][3] + pbv.w + X[addr + 12288];
        }
      }
    }
  }
}

// ---------- launcher ----------
// Pipeline (D = d_out, A = 128 MiB scratch):
//   1. dwffn0: x -> D
//   2. attn:   D -> A
//   3. dwffn1: A -> D
extern "C" void kernel_launch(void* const* d_in, const int* in_sizes, int n_in, void* d_out, int out_size,
                              void* d_ws, size_t ws_size, hipStream_t stream) {
  const float* x = (const float*)d_in[0];
  const float* dw0_w = (const float*)d_in[1];
  const float* dw0_s = (const float*)d_in[2];
  const float* dw0_b = (const float*)d_in[3];
  const float* f0_w1 = (const float*)d_in[4];
  const float* f0_s1 = (const float*)d_in[5];
  const float* f0_b1 = (const float*)d_in[6];
  const float* f0_w2 = (const float*)d_in[7];
  const float* f0_s2 = (const float*)d_in[8];
  const float* f0_b2 = (const float*)d_in[9];
  const float* wq = (const float*)d_in[10];
  const float* wkv = (const float*)d_in[11];
  const float* pos = (const float*)d_in[12];
  const float* scale_p = (const float*)d_in[13];
  const float* dwc_w = (const float*)d_in[14];
  const float* dwc_b = (const float*)d_in[15];
  const float* proj_w = (const float*)d_in[16];
  const float* proj_b = (const float*)d_in[17];
  const float* dw1_w = (const float*)d_in[18];
  const float* dw1_s = (const float*)d_in[19];
  const float* dw1_b = (const float*)d_in[20];
  const float* f1_w1 = (const float*)d_in[21];
  const float* f1_s1 = (const float*)d_in[22];
  const float* f1_b1 = (const float*)d_in[23];
  const float* f1_w2 = (const float*)d_in[24];
  const float* f1_s2 = (const float*)d_in[25];
  const float* f1_b2 = (const float*)d_in[26];

  float* D = (float*)d_out;
  const size_t nbytes = (size_t)out_size * sizeof(float);  // 134,217,728
  float* A = (ws_size >= nbytes) ? (float*)d_ws : (float*)d_in[0];

  (void)hipFuncSetAttribute((const void*)attn_kernel, hipFuncAttributeMaxDynamicSharedMemorySize, SMEM_BYTES);

  dwffn<<<dim3(128, 32), 256, 0, stream>>>(x, D, dw0_w, dw0_s, dw0_b, f0_w1, f0_s1, f0_b1, f0_w2, f0_s2, f0_b2);
  attn_kernel<<<3200, 512, SMEM_BYTES, stream>>>(D, wq, wkv, pos, scale_p, dwc_w, dwc_b, proj_w, proj_b, A);
  dwffn<<<dim3(128, 32), 256, 0, stream>>>(A, D, dw1_w, dw1_s, dw1_b, f1_w1, f1_s1, f1_b1, f1_w2, f1_s2, f1_b2);
}

// Round 10
// 2614.879 us; speedup vs baseline: 5.5434x; 1.1308x over previous
//
#include <hip/hip_runtime.h>

typedef unsigned short u16;
typedef unsigned int u32;
typedef __attribute__((ext_vector_type(8))) short bf16x8;   // 8 bf16 = 4 VGPRs (MFMA A/B frag)
typedef __attribute__((ext_vector_type(4))) float f32x4;    // MFMA C/D frag

// ---------- bf16 <-> fp32 helpers (LDS staging only; global I/O is fp32) ----------
__device__ __forceinline__ float b2f(u16 v) { return __uint_as_float(((u32)v) << 16); }
__device__ __forceinline__ u16 f2b(float f) {
  u32 u = __float_as_uint(f);
  u32 r = (u + 0x7fffu + ((u >> 16) & 1u)) >> 16;  // RNE
  return (u16)r;
}
__device__ __forceinline__ void unpack8(uint4 u, float* f) {
  f[0] = __uint_as_float(u.x << 16);
  f[1] = __uint_as_float(u.x & 0xffff0000u);
  f[2] = __uint_as_float(u.y << 16);
  f[3] = __uint_as_float(u.y & 0xffff0000u);
  f[4] = __uint_as_float(u.z << 16);
  f[5] = __uint_as_float(u.z & 0xffff0000u);
  f[6] = __uint_as_float(u.w << 16);
  f[7] = __uint_as_float(u.w & 0xffff0000u);
}
__device__ __forceinline__ uint4 pack8(const u16* o) {
  return make_uint4((u32)o[0] | ((u32)o[1] << 16), (u32)o[2] | ((u32)o[3] << 16),
                    (u32)o[4] | ((u32)o[5] << 16), (u32)o[6] | ((u32)o[7] << 16));
}
// truncate-pack 8 fp32 -> bf16x8 (weights only; error << activation RNE already present)
__device__ __forceinline__ bf16x8 pkbf8(float4 a, float4 b) {
  union { uint4 u; bf16x8 v; } r;
  r.u.x = (__float_as_uint(a.x) >> 16) | (__float_as_uint(a.y) & 0xffff0000u);
  r.u.y = (__float_as_uint(a.z) >> 16) | (__float_as_uint(a.w) & 0xffff0000u);
  r.u.z = (__float_as_uint(b.x) >> 16) | (__float_as_uint(b.y) & 0xffff0000u);
  r.u.w = (__float_as_uint(b.z) >> 16) | (__float_as_uint(b.w) & 0xffff0000u);
  return r.v;
}

// ---------- fused [dw3x3+BN+res] -> [1x1 BN relu] -> [1x1 BN + res], MFMA GEMMs ----------
// 512 threads (8 waves), 48 KiB LDS, launch_bounds(512,4) => VGPR<=128 => 2 blocks/CU (16 waves).
// Same math as the verified 256-thread version; only the work distribution changed.
__global__ __launch_bounds__(512, 4) void dwffn(const float* __restrict__ X, float* __restrict__ Y,
                                                const float* __restrict__ DwW, const float* __restrict__ DwS,
                                                const float* __restrict__ DwB, const float* __restrict__ W1,
                                                const float* __restrict__ S1, const float* __restrict__ B1,
                                                const float* __restrict__ W2, const float* __restrict__ S2,
                                                const float* __restrict__ B2) {
  __shared__ __align__(16) u16 X1s[32 * 256];  // 16 KiB, [px][c] swizzled
  __shared__ __align__(16) u16 Hs[32 * 512];   // 32 KiB, [px][h] swizzled
  const int tid = threadIdx.x;
  const int pix0 = blockIdx.x << 5;
  const long zbase = (long)blockIdx.y * 1048576L;
  const int h0 = pix0 >> 6, w0 = pix0 & 63;

  // phase A: X1 = x + s*dw3x3(x) + b  -> X1s[px][c] (bf16, swizzled); 16 channels/thread
  {
    const int px = tid & 31;
    const int cg = tid >> 5;  // 0..15
    const int w = w0 + px;
    const int sw = (px & 7) << 3;
    for (int it = 0; it < 4; ++it) {
      const int c0 = it * 64 + cg * 4;
      u16 o[4];
#pragma unroll
      for (int cc = 0; cc < 4; ++cc) {
        const int c = c0 + cc;
        const float* xp = X + zbase + (long)c * 4096;
        float acc = 0.f;
#pragma unroll
        for (int u = 0; u < 3; u++) {
          int hh = h0 + u - 1;
          if (hh < 0 || hh > 63) continue;
#pragma unroll
          for (int v = 0; v < 3; v++) {
            int wv2 = w + v - 1;
            if (wv2 < 0 || wv2 > 63) continue;
            acc = fmaf(DwW[c * 9 + u * 3 + v], xp[hh * 64 + wv2], acc);
          }
        }
        o[cc] = f2b(xp[h0 * 64 + w] + fmaf(DwS[c], acc, DwB[c]));
      }
      *(uint2*)&X1s[px * 256 + (c0 ^ sw)] =
          make_uint2((u32)o[0] | ((u32)o[1] << 16), (u32)o[2] | ((u32)o[3] << 16));
    }
  }
  __syncthreads();

  const int lane = tid & 63, wv = tid >> 6;  // wv 0..7
  const int l15 = lane & 15, lg = lane >> 4;

  // GEMM1: hidden = relu(s1*(W1 @ X1) + b1); wave owns M-tiles {wv + 8*mt}, mt<4
  {
    f32x4 acc1[4][2];
#pragma unroll
    for (int mt = 0; mt < 4; mt++)
#pragma unroll
      for (int nt = 0; nt < 2; nt++) acc1[mt][nt] = (f32x4){0.f, 0.f, 0.f, 0.f};
    for (int kst = 0; kst < 8; ++kst) {
      const int k0 = kst * 32 + lg * 8;
      bf16x8 bq[2];
#pragma unroll
      for (int nt = 0; nt < 2; nt++) {
        const int pxn = nt * 16 + l15;
        bq[nt] = *(const bf16x8*)&X1s[pxn * 256 + (k0 ^ ((pxn & 7) << 3))];
      }
#pragma unroll
      for (int mt = 0; mt < 4; mt++) {
        const int hrow = ((wv + (mt << 3)) << 4) + l15;
        const float* wr = W1 + hrow * 256 + k0;
        bf16x8 af = pkbf8(*(const float4*)wr, *(const float4*)(wr + 4));
        acc1[mt][0] = __builtin_amdgcn_mfma_f32_16x16x32_bf16(af, bq[0], acc1[mt][0], 0, 0, 0);
        acc1[mt][1] = __builtin_amdgcn_mfma_f32_16x16x32_bf16(af, bq[1], acc1[mt][1], 0, 0, 0);
      }
    }
#pragma unroll
    for (int mt = 0; mt < 4; mt++) {
      const int hq = ((wv + (mt << 3)) << 4) + lg * 4;
      const float4 s1v = *(const float4*)(S1 + hq);
      const float4 b1v = *(const float4*)(B1 + hq);
#pragma unroll
      for (int nt = 0; nt < 2; nt++) {
        const int pxn = nt * 16 + l15;
        u16 o[4];
        o[0] = f2b(fmaxf(fmaf(s1v.x, acc1[mt][nt][0], b1v.x), 0.f));
        o[1] = f2b(fmaxf(fmaf(s1v.y, acc1[mt][nt][1], b1v.y), 0.f));
        o[2] = f2b(fmaxf(fmaf(s1v.z, acc1[mt][nt][2], b1v.z), 0.f));
        o[3] = f2b(fmaxf(fmaf(s1v.w, acc1[mt][nt][3], b1v.w), 0.f));
        *(uint2*)&Hs[pxn * 512 + (hq ^ ((pxn & 7) << 3))] =
            make_uint2((u32)o[0] | ((u32)o[1] << 16), (u32)o[2] | ((u32)o[3] << 16));
      }
    }
  }
  __syncthreads();

  // GEMM2: out = s2*(W2 @ H) + b2 + X1; wave owns M-tiles {wv + 8*mt}, mt<2
  {
    f32x4 acc2[2][2];
#pragma unroll
    for (int mt = 0; mt < 2; mt++)
#pragma unroll
      for (int nt = 0; nt < 2; nt++) acc2[mt][nt] = (f32x4){0.f, 0.f, 0.f, 0.f};
    for (int kst = 0; kst < 16; ++kst) {
      const int k0 = kst * 32 + lg * 8;
      bf16x8 bq[2];
#pragma unroll
      for (int nt = 0; nt < 2; nt++) {
        const int pxn = nt * 16 + l15;
        bq[nt] = *(const bf16x8*)&Hs[pxn * 512 + (k0 ^ ((pxn & 7) << 3))];
      }
#pragma unroll
      for (int mt = 0; mt < 2; mt++) {
        const int crow = ((wv + (mt << 3)) << 4) + l15;
        const float* wr = W2 + crow * 512 + k0;
        bf16x8 af = pkbf8(*(const float4*)wr, *(const float4*)(wr + 4));
        acc2[mt][0] = __builtin_amdgcn_mfma_f32_16x16x32_bf16(af, bq[0], acc2[mt][0], 0, 0, 0);
        acc2[mt][1] = __builtin_amdgcn_mfma_f32_16x16x32_bf16(af, bq[1], acc2[mt][1], 0, 0, 0);
      }
    }
#pragma unroll
    for (int mt = 0; mt < 2; mt++) {
      const int coq = ((wv + (mt << 3)) << 4) + lg * 4;
      const float4 s2v = *(const float4*)(S2 + coq);
      const float4 b2v = *(const float4*)(B2 + coq);
#pragma unroll
      for (int nt = 0; nt < 2; nt++) {
        const int pxn = nt * 16 + l15;
        uint2 rv = *(const uint2*)&X1s[pxn * 256 + (coq ^ ((pxn & 7) << 3))];
        float rr0 = __uint_as_float(rv.x << 16);
        float rr1 = __uint_as_float(rv.x & 0xffff0000u);
        float rr2 = __uint_as_float(rv.y << 16);
        float rr3 = __uint_as_float(rv.y & 0xffff0000u);
        float* yp = Y + zbase + (long)coq * 4096 + pix0 + pxn;
        yp[0] = fmaf(s2v.x, acc2[mt][nt][0], b2v.x) + rr0;
        yp[4096] = fmaf(s2v.y, acc2[mt][nt][1], b2v.y) + rr1;
        yp[8192] = fmaf(s2v.z, acc2[mt][nt][2], b2v.z) + rr2;
        yp[12288] = fmaf(s2v.w, acc2[mt][nt][3], b2v.w) + rr3;
      }
    }
  }
}

// ---------- fused windowed focused-linear attention, full-MFMA (src != dst) ----------
// 1024 threads (16 waves) per window block; same LDS (139,776 B, 1 block/CU) but 4 waves/SIMD.
// Same math as the verified 512-thread version; only the per-wave job distribution changed.
// NOTE: dwc weights/bias indexed by HEAD-channel (d & 63), shared across the 4 heads!
#define NTOK 49
#define AOFF_XW 0        // [64 tok][256 ch] gather input; later QK[4][64][64] (dead after GEMM-P)
#define AOFF_SQB 32768   // [64 tok][256 ch] q; later attn-out (dead after qk)
#define AOFF_SKB 65536   // [64 tok][256 ch] k
#define AOFF_SVT 98304   // [256 ch][64 tok] v, d-major
#define AOFF_SDW 131072  // fp32 1600 dwc w + 64 bias = 6656 B
#define AOFF_SSC 137728  // fp32 256 softplus
#define AOFF_SZ 138752   // fp32 256 z (h*64+i)
#define SMEM_BYTES 139776

__global__ __launch_bounds__(1024) void attn_kernel(const float* __restrict__ X, const float* __restrict__ Wq,
                                                    const float* __restrict__ Wkv, const float* __restrict__ Pos,
                                                    const float* __restrict__ ScaleP, const float* __restrict__ DwcW,
                                                    const float* __restrict__ DwcB, const float* __restrict__ PrW,
                                                    const float* __restrict__ PrB, float* __restrict__ Y) {
  extern __shared__ char smem[];
  u16* XW = (u16*)(smem + AOFF_XW);    // gather; later QK
  u16* QKB = (u16*)(smem + AOFF_XW);   // alias
  u16* SQB = (u16*)(smem + AOFF_SQB);  // q; later attn-out
  u16* AO = (u16*)(smem + AOFF_SQB);   // alias
  u16* SKB = (u16*)(smem + AOFF_SKB);
  u16* SVT = (u16*)(smem + AOFF_SVT);
  float* SDW = (float*)(smem + AOFF_SDW);
  float* SSC = (float*)(smem + AOFF_SSC);
  float* SZ = (float*)(smem + AOFF_SZ);

  const int tid = threadIdx.x;
  const int wi = blockIdx.x;
  const int b = wi / 100;
  const int rem = wi - b * 100;
  const int wh = rem / 10, ww = rem - (rem / 10) * 10;
  const long bbase = (long)b * (256L * 4096L);

  // softplus(scale_p); dwc weights+bias -> LDS
  if (tid < 256) SSC[tid] = log1pf(expf(ScaleP[tid]));
  for (int i = tid; i < 1600; i += 1024) SDW[i] = DwcW[i];
  if (tid < 64) SDW[1600 + tid] = DwcB[tid];

  // zero SQB/SKB/SVT entirely (pad rows/cols MUST be 0 — MFMA pads multiply by them).
  // 3 regions x 32768 B = 6144 uint4 exactly (do NOT overrun into SDW/SSC/SZ).
  {
    const uint4 z4 = make_uint4(0, 0, 0, 0);
    uint4* zb = (uint4*)(smem + AOFF_SQB);
    for (int e = tid; e < 6144; e += 1024) zb[e] = z4;
  }

  // gather window -> XW bf16 [64tok][256c] swizzled, zero-padded
  for (int u = tid; u < 64 * 32; u += 1024) {
    const int cg = u >> 6, t = u & 63;
    const int c0 = cg << 3;
    u16 o[8] = {0, 0, 0, 0, 0, 0, 0, 0};
    if (t < NTOK) {
      const int r = t / 7, cc = t - r * 7;
      const int gh = wh * 7 + r, gw = ww * 7 + cc;
      if (gh < 64 && gw < 64) {
        const float* xp = X + bbase + gh * 64 + gw;
#pragma unroll
        for (int e = 0; e < 8; e++) o[e] = f2b(xp[(long)(c0 + e) * 4096]);
      }
    }
    *(uint4*)&XW[t * 256 + (c0 ^ ((t & 7) << 3))] = pack8(o);
  }
  __syncthreads();

  const int lane = tid & 63, wvid = tid >> 6;  // wvid 0..15
  const int l15 = lane & 15, lg = lane >> 4;

  // GEMM-P: wave owns M-tiles {wvid + 16*mt}, mt<3 — one q-tile, one k-tile, one v-tile
  {
    const float* wr_base[3];
    int tile[3];
#pragma unroll
    for (int mt = 0; mt < 3; mt++) {
      const int tl = wvid + (mt << 4);
      tile[mt] = tl;
      const int row = (tl << 4) + l15;
      wr_base[mt] = (row < 256) ? (Wq + row * 256) : (Wkv + (row - 256) * 256);
    }
    f32x4 acc[3][4];
#pragma unroll
    for (int mt = 0; mt < 3; mt++)
#pragma unroll
      for (int nt = 0; nt < 4; nt++) acc[mt][nt] = (f32x4){0.f, 0.f, 0.f, 0.f};
    for (int kst = 0; kst < 8; ++kst) {
      const int k0 = kst * 32 + lg * 8;
      bf16x8 bq[4];
#pragma unroll
      for (int nt = 0; nt < 4; nt++) {
        const int tkn = (nt << 4) + l15;
        bq[nt] = *(const bf16x8*)&XW[tkn * 256 + (k0 ^ ((tkn & 7) << 3))];
      }
#pragma unroll
      for (int mt = 0; mt < 3; mt++) {
        bf16x8 af = pkbf8(*(const float4*)(wr_base[mt] + k0), *(const float4*)(wr_base[mt] + k0 + 4));
#pragma unroll
        for (int nt = 0; nt < 4; nt++)
          acc[mt][nt] = __builtin_amdgcn_mfma_f32_16x16x32_bf16(af, bq[nt], acc[mt][nt], 0, 0, 0);
      }
    }
    // epilogues: q -> SQB bf16; k -> (+pos, relu, /sc) SKB bf16; v -> SVT d-major bf16
#pragma unroll
    for (int mt = 0; mt < 3; mt++) {
      const int tl = tile[mt];
#pragma unroll
      for (int nt = 0; nt < 4; nt++) {
        const int tkn = (nt << 4) + l15;
        if (tkn >= NTOK) continue;
        const int sw = (tkn & 7) << 3;
        if (tl < 16) {
          const int jq = (tl << 4) + (lg << 2);
          const float4 sc = *(const float4*)(SSC + jq);
          u16 o[4];
          o[0] = f2b((fmaxf(acc[mt][nt][0], 0.f) + 1e-6f) / sc.x);
          o[1] = f2b((fmaxf(acc[mt][nt][1], 0.f) + 1e-6f) / sc.y);
          o[2] = f2b((fmaxf(acc[mt][nt][2], 0.f) + 1e-6f) / sc.z);
          o[3] = f2b((fmaxf(acc[mt][nt][3], 0.f) + 1e-6f) / sc.w);
          *(uint2*)&SQB[tkn * 256 + (jq ^ sw)] = make_uint2((u32)o[0] | ((u32)o[1] << 16), (u32)o[2] | ((u32)o[3] << 16));
        } else if (tl < 32) {
          const int kc = ((tl - 16) << 4) + (lg << 2);
          const float4 sc = *(const float4*)(SSC + kc);
          const float4 pp = *(const float4*)(Pos + tkn * 256 + kc);
          u16 o[4];
          o[0] = f2b((fmaxf(acc[mt][nt][0] + pp.x, 0.f) + 1e-6f) / sc.x);
          o[1] = f2b((fmaxf(acc[mt][nt][1] + pp.y, 0.f) + 1e-6f) / sc.y);
          o[2] = f2b((fmaxf(acc[mt][nt][2] + pp.z, 0.f) + 1e-6f) / sc.z);
          o[3] = f2b((fmaxf(acc[mt][nt][3] + pp.w, 0.f) + 1e-6f) / sc.w);
          *(uint2*)&SKB[tkn * 256 + (kc ^ sw)] = make_uint2((u32)o[0] | ((u32)o[1] << 16), (u32)o[2] | ((u32)o[3] << 16));
        } else {
          const int vc = ((tl - 32) << 4) + (lg << 2);
#pragma unroll
          for (int cc = 0; cc < 4; cc++) {
            const int d = vc + cc;
            SVT[d * 64 + (tkn ^ ((d & 7) << 3))] = f2b(acc[mt][nt][cc]);
          }
        }
      }
    }
  }
  __syncthreads();

  // focus: t^3 renorm to original L2 over C=256 (bf16 in/out), one wave per token
  for (int t = wvid; t < NTOK; t += 16) {
    const int sw = (t & 7) << 3;
    float qv[4], ss = 0.f, s6 = 0.f;
#pragma unroll
    for (int m = 0; m < 4; m++) {
      float v = b2f(SQB[t * 256 + ((lane + (m << 6)) ^ sw)]);
      qv[m] = v;
      ss += v * v;
      float c3 = v * v * v;
      s6 += c3 * c3;
    }
#pragma unroll
    for (int off = 1; off < 64; off <<= 1) {
      ss += __shfl_xor(ss, off, 64);
      s6 += __shfl_xor(s6, off, 64);
    }
    float scl = sqrtf(ss) / sqrtf(s6);
#pragma unroll
    for (int m = 0; m < 4; m++) {
      float v = qv[m];
      SQB[t * 256 + ((lane + (m << 6)) ^ sw)] = f2b(v * v * v * scl);
    }
    float kv[4];
    ss = 0.f;
    s6 = 0.f;
#pragma unroll
    for (int m = 0; m < 4; m++) {
      float v = b2f(SKB[t * 256 + ((lane + (m << 6)) ^ sw)]);
      kv[m] = v;
      ss += v * v;
      float c3 = v * v * v;
      s6 += c3 * c3;
    }
#pragma unroll
    for (int off = 1; off < 64; off <<= 1) {
      ss += __shfl_xor(ss, off, 64);
      s6 += __shfl_xor(s6, off, 64);
    }
    scl = sqrtf(ss) / sqrtf(s6);
#pragma unroll
    for (int m = 0; m < 4; m++) {
      float v = kv[m];
      SKB[t * 256 + ((lane + (m << 6)) ^ sw)] = f2b(v * v * v * scl);
    }
  }
  __syncthreads();

  // qk MFMA: QK[h][i][j] = q_i . k_j over d=64; 64 tile-jobs, 4 per wave
  for (int jj = 0; jj < 4; ++jj) {
    const int job = (jj << 4) + wvid;
    const int h = job >> 4;
    const int r2 = job & 15;
    const int ti = r2 >> 2, tj = r2 & 3;
    const int hb = h << 6;
    f32x4 a = (f32x4){0.f, 0.f, 0.f, 0.f};
#pragma unroll
    for (int kst = 0; kst < 2; ++kst) {
      const int k0 = hb + kst * 32 + lg * 8;
      const int irow = ti * 16 + l15;
      const int jrow = tj * 16 + l15;
      bf16x8 qa = *(const bf16x8*)&SQB[irow * 256 + (k0 ^ ((irow & 7) << 3))];
      bf16x8 kb = *(const bf16x8*)&SKB[jrow * 256 + (k0 ^ ((jrow & 7) << 3))];
      a = __builtin_amdgcn_mfma_f32_16x16x32_bf16(qa, kb, a, 0, 0, 0);
    }
#pragma unroll
    for (int reg = 0; reg < 4; ++reg) {
      const int i = ti * 16 + lg * 4 + reg, j = tj * 16 + l15;
      QKB[((h << 6) + i) * 64 + (j ^ ((i & 7) << 3))] = f2b(a[reg]);
    }
  }
  __syncthreads();

  // z[h][i] = 1/(row-sum QK + 1e-6); swizzle permutes within the row, sum is order-free
  if (tid < 256) {
    const uint4* rowp = (const uint4*)&QKB[tid * 64];
    float s = 0.f;
#pragma unroll
    for (int k = 0; k < 8; k++) {
      uint4 uu = rowp[(k + tid) & 7];  // staggered start: avoid all-lanes-same-bank
      float f[8];
      unpack8(uu, f);
#pragma unroll
      for (int e = 0; e < 8; e++) s += f[e];
    }
    SZ[tid] = 1.f / (s + 1e-6f);
  }
  __syncthreads();

  // PV MFMA: y[i][d] = z_i * sum_j QK[i][j] V[j][d]; 64 tile-jobs, 4 per wave
  for (int jj = 0; jj < 4; ++jj) {
    const int job = (jj << 4) + wvid;
    const int ti = job >> 4;
    const int dt = job & 15;
    const int h = dt >> 2;
    f32x4 a = (f32x4){0.f, 0.f, 0.f, 0.f};
#pragma unroll
    for (int kst = 0; kst < 2; ++kst) {
      const int j0 = kst * 32 + lg * 8;
      const int irow = ti * 16 + l15;
      const int drow = (dt << 4) + l15;
      bf16x8 qk = *(const bf16x8*)&QKB[((h << 6) + irow) * 64 + (j0 ^ ((irow & 7) << 3))];
      bf16x8 vt = *(const bf16x8*)&SVT[drow * 64 + (j0 ^ ((drow & 7) << 3))];
      a = __builtin_amdgcn_mfma_f32_16x16x32_bf16(qk, vt, a, 0, 0, 0);
    }
#pragma unroll
    for (int reg = 0; reg < 4; ++reg) {
      const int i = ti * 16 + lg * 4 + reg;
      const int d = (dt << 4) + l15;
      const float z = SZ[(h << 6) + i];
      AO[i * 256 + (d ^ ((i & 7) << 3))] = f2b(a[reg] * z);
    }
  }
  __syncthreads();

  // dw5x5 on v, d-major: thread = (channel d, row-quarter); RMW-add into attn-out.
  // dwc filter/bias are PER-HEAD-CHANNEL: index with dch = d & 63 (shared across heads).
  {
    const int d = tid >> 2;        // 0..255
    const int q4 = tid & 3;        // row quarter: {0,1},{2,3},{4,5},{6}
    const int dch = d & 63;
    const float bias = SDW[1600 + dch];
    const int swd = (d & 7) << 3;
    const u16* vrow = SVT + d * 64;
    const float* wrow = SDW + dch * 25;
    const int rlo = q4 * 2, rhi = (q4 == 3) ? 7 : (q4 * 2 + 2);
    for (int r = rlo; r < rhi; ++r) {
      for (int c = 0; c < 7; ++c) {
        float fm = bias;
#pragma unroll
        for (int u = 0; u < 5; u++) {
          const int rr = r + u - 2;
          if (rr < 0 || rr > 6) continue;
#pragma unroll
          for (int v = 0; v < 5; v++) {
            const int cc = c + v - 2;
            if (cc < 0 || cc > 6) continue;
            fm = fmaf(b2f(vrow[(rr * 7 + cc) ^ swd]), wrow[u * 5 + v], fm);
          }
        }
        const int t = r * 7 + c;
        const int idx = t * 256 + (d ^ ((t & 7) << 3));
        AO[idx] = f2b(b2f(AO[idx]) + fm);
      }
    }
  }
  __syncthreads();

  // GEMM-O: out = PrW @ attn-out + bias + residual; wave owns one 16-row tile
  {
    f32x4 acc[4];
#pragma unroll
    for (int nt = 0; nt < 4; nt++) acc[nt] = (f32x4){0.f, 0.f, 0.f, 0.f};
    const int cbase = wvid << 4;
    for (int kst = 0; kst < 8; ++kst) {
      const int k0 = kst * 32 + lg * 8;
      bf16x8 bq[4];
#pragma unroll
      for (int nt = 0; nt < 4; nt++) {
        const int tkn = (nt << 4) + l15;
        bq[nt] = *(const bf16x8*)&AO[tkn * 256 + (k0 ^ ((tkn & 7) << 3))];
      }
      const float* wr = PrW + (cbase + l15) * 256 + k0;
      bf16x8 af = pkbf8(*(const float4*)wr, *(const float4*)(wr + 4));
#pragma unroll
      for (int nt = 0; nt < 4; nt++)
        acc[nt] = __builtin_amdgcn_mfma_f32_16x16x32_bf16(af, bq[nt], acc[nt], 0, 0, 0);
    }
    const int coq = cbase + (lg << 2);
    const float4 pbv = *(const float4*)(PrB + coq);
#pragma unroll
    for (int nt = 0; nt < 4; nt++) {
      const int tkn = (nt << 4) + l15;
      if (tkn >= NTOK) continue;
      const int r = tkn / 7, cc = tkn - r * 7;
      const int gh = wh * 7 + r, gw = ww * 7 + cc;
      if (gh < 64 && gw < 64) {
        const long addr = bbase + (long)coq * 4096 + gh * 64 + gw;
        Y[addr] = acc[nt][0] + pbv.x + X[addr];
        Y[addr + 4096] = acc[nt][1] + pbv.y + X[addr + 4096];
        Y[addr + 8192] = acc[nt][2] + pbv.z + X[addr + 8192];
        Y[addr + 12288] = acc[nt][3] + pbv.w + X[addr + 12288];
      }
    }
  }
}

// ---------- launcher ----------
// Pipeline (D = d_out, A = 128 MiB scratch):
//   1. dwffn0: x -> D
//   2. attn:   D -> A
//   3. dwffn1: A -> D
extern "C" void kernel_launch(void* const* d_in, const int* in_sizes, int n_in, void* d_out, int out_size,
                              void* d_ws, size_t ws_size, hipStream_t stream) {
  const float* x = (const float*)d_in[0];
  const float* dw0_w = (const float*)d_in[1];
  const float* dw0_s = (const float*)d_in[2];
  const float* dw0_b = (const float*)d_in[3];
  const float* f0_w1 = (const float*)d_in[4];
  const float* f0_s1 = (const float*)d_in[5];
  const float* f0_b1 = (const float*)d_in[6];
  const float* f0_w2 = (const float*)d_in[7];
  const float* f0_s2 = (const float*)d_in[8];
  const float* f0_b2 = (const float*)d_in[9];
  const float* wq = (const float*)d_in[10];
  const float* wkv = (const float*)d_in[11];
  const float* pos = (const float*)d_in[12];
  const float* scale_p = (const float*)d_in[13];
  const float* dwc_w = (const float*)d_in[14];
  const float* dwc_b = (const float*)d_in[15];
  const float* proj_w = (const float*)d_in[16];
  const float* proj_b = (const float*)d_in[17];
  const float* dw1_w = (const float*)d_in[18];
  const float* dw1_s = (const float*)d_in[19];
  const float* dw1_b = (const float*)d_in[20];
  const float* f1_w1 = (const float*)d_in[21];
  const float* f1_s1 = (const float*)d_in[22];
  const float* f1_b1 = (const float*)d_in[23];
  const float* f1_w2 = (const float*)d_in[24];
  const float* f1_s2 = (const float*)d_in[25];
  const float* f1_b2 = (const float*)d_in[26];

  float* D = (float*)d_out;
  const size_t nbytes = (size_t)out_size * sizeof(float);  // 134,217,728
  float* A = (ws_size >= nbytes) ? (float*)d_ws : (float*)d_in[0];

  (void)hipFuncSetAttribute((const void*)attn_kernel, hipFuncAttributeMaxDynamicSharedMemorySize, SMEM_BYTES);

  dwffn<<<dim3(128, 32), 512, 0, stream>>>(x, D, dw0_w, dw0_s, dw0_b, f0_w1, f0_s1, f0_b1, f0_w2, f0_s2, f0_b2);
  attn_kernel<<<3200, 1024, SMEM_BYTES, stream>>>(D, wq, wkv, pos, scale_p, dwc_w, dwc_b, proj_w, proj_b, A);
  dwffn<<<dim3(128, 32), 512, 0, stream>>>(A, D, dw1_w, dw1_s, dw1_b, f1_w1, f1_s1, f1_b1, f1_w2, f1_s2, f1_b2);
}